// Round 1
// baseline (313.482 us; speedup 1.0000x reference)
//
#include <hip/hip_runtime.h>
#include <stdint.h>

typedef unsigned short u16;
typedef __attribute__((ext_vector_type(8))) short bf16x8;
typedef __attribute__((ext_vector_type(4))) float f32x4;

#define BATCH 2
#define SEQ 2048
#define NH 16
#define HDIM 64
#define DMODEL 1024
#define MTOT (BATCH * SEQ)      // 4096
#define QKV_N (3 * DMODEL)      // 3072
#define ATT_SCALE 0.125f
#define L2E 1.44269504088896340736f

// ---- helpers ----------------------------------------------------------
__device__ __forceinline__ u16 f2b(float f) {   // fp32 -> bf16 (RNE)
    uint32_t x = __builtin_bit_cast(uint32_t, f);
    uint32_t r = (x + 0x7fffu + ((x >> 16) & 1u)) >> 16;
    return (u16)r;
}

__device__ __forceinline__ void gl_lds16(const void* g, void* l) {
    // async global->LDS, 16B per lane; LDS dest is wave-uniform base + lane*16
    __builtin_amdgcn_global_load_lds(
        (const __attribute__((address_space(1))) void*)g,
        (__attribute__((address_space(3))) void*)l, 16, 0, 0);
}

// ---- kernel 1: fp32 -> bf16 elementwise ------------------------------
__global__ __launch_bounds__(256) void k_cvt(const float* __restrict__ in,
                                             u16* __restrict__ out, int n8) {
    int i = blockIdx.x * blockDim.x + threadIdx.x;
    if (i >= n8) return;
    const float4* p = (const float4*)in + (size_t)i * 2;
    float4 a = p[0], b = p[1];
    union { u16 t[8]; uint4 v; } u;
    u.t[0] = f2b(a.x); u.t[1] = f2b(a.y); u.t[2] = f2b(a.z); u.t[3] = f2b(a.w);
    u.t[4] = f2b(b.x); u.t[5] = f2b(b.y); u.t[6] = f2b(b.z); u.t[7] = f2b(b.w);
    *(uint4*)(out + (size_t)i * 8) = u.v;
}

// ---- kernel 2: W[rows][cols] fp32 -> WT[cols][rows] bf16 -------------
__global__ __launch_bounds__(256) void k_wtrans(const float* __restrict__ W,
                                                u16* __restrict__ WT,
                                                int rows, int cols) {
    __shared__ float tile[64][65];
    const int c0 = blockIdx.x * 64, r0 = blockIdx.y * 64;
    const int tx = threadIdx.x & 63, ty = threadIdx.x >> 6;
#pragma unroll
    for (int i = 0; i < 16; ++i) {
        int r = i * 4 + ty;
        tile[r][tx] = W[(size_t)(r0 + r) * cols + c0 + tx];
    }
    __syncthreads();
#pragma unroll
    for (int i = 0; i < 16; ++i) {
        int c = i * 4 + ty;
        WT[(size_t)(c0 + c) * rows + r0 + tx] = f2b(tile[tx][c]);
    }
}

// ---- kernel 3/6: C[M,N] = A[M,K] * BT[N,K]^T  (bf16 in, bf16/f32 out)
template <bool F32OUT>
__global__ __launch_bounds__(256) void k_gemm_bt(const u16* __restrict__ A,
                                                 const u16* __restrict__ BT,
                                                 void* __restrict__ C,
                                                 int M, int N, int K) {
    __shared__ __align__(16) u16 As[128 * 64];
    __shared__ __align__(16) u16 Bs[128 * 64];
    const int tid = threadIdx.x;
    const int wid = tid >> 6, lane = tid & 63;
    const int r = lane & 15, g = lane >> 4;
    const int m0 = blockIdx.y * 128, n0 = blockIdx.x * 128;
    const int wm = (wid >> 1) * 64, wn = (wid & 1) * 64;
    const int srow = lane >> 3, scol = (lane & 7) * 8;
    f32x4 acc[4][4] = {};
    for (int k0 = 0; k0 < K; k0 += 64) {
#pragma unroll
        for (int i = 0; i < 4; ++i) {
            const int li = wid * 4 + i;
            gl_lds16(A + (size_t)(m0 + li * 8 + srow) * K + k0 + scol, &As[li * 512]);
            gl_lds16(BT + (size_t)(n0 + li * 8 + srow) * K + k0 + scol, &Bs[li * 512]);
        }
        __syncthreads();
#pragma unroll
        for (int kk = 0; kk < 2; ++kk) {
            bf16x8 af[4], bfr[4];
#pragma unroll
            for (int mi = 0; mi < 4; ++mi)
                af[mi] = *(const bf16x8*)&As[(wm + mi * 16 + r) * 64 + kk * 32 + g * 8];
#pragma unroll
            for (int ni = 0; ni < 4; ++ni)
                bfr[ni] = *(const bf16x8*)&Bs[(wn + ni * 16 + r) * 64 + kk * 32 + g * 8];
#pragma unroll
            for (int mi = 0; mi < 4; ++mi)
#pragma unroll
                for (int ni = 0; ni < 4; ++ni)
                    acc[mi][ni] = __builtin_amdgcn_mfma_f32_16x16x32_bf16(
                        af[mi], bfr[ni], acc[mi][ni], 0, 0, 0);
        }
        __syncthreads();
    }
#pragma unroll
    for (int mi = 0; mi < 4; ++mi)
#pragma unroll
        for (int ni = 0; ni < 4; ++ni) {
            const int col = n0 + wn + ni * 16 + r;
#pragma unroll
            for (int e = 0; e < 4; ++e) {
                const int row = m0 + wm + mi * 16 + g * 4 + e;
                if (F32OUT)
                    ((float*)C)[(size_t)row * N + col] = acc[mi][ni][e];
                else
                    ((u16*)C)[(size_t)row * N + col] = f2b(acc[mi][ni][e]);
            }
        }
}

// ---- kernel 4: Vt[b][h][hd][s] <- qkv V slice ------------------------
__global__ __launch_bounds__(256) void k_vtrans(const u16* __restrict__ qkv,
                                                u16* __restrict__ Vt) {
    __shared__ u16 tile[64][65];
    const int bh = blockIdx.y;
    const int b = bh >> 4, h = bh & 15;
    const int s0 = blockIdx.x * 64;
    const int tx = threadIdx.x & 63, ty = threadIdx.x >> 6;
#pragma unroll
    for (int i = 0; i < 16; ++i) {
        int s = i * 4 + ty;
        tile[s][tx] = qkv[(size_t)(b * SEQ + s0 + s) * QKV_N + 2 * DMODEL + h * HDIM + tx];
    }
    __syncthreads();
#pragma unroll
    for (int i = 0; i < 16; ++i) {
        int hd = i * 4 + ty;
        Vt[((size_t)bh * HDIM + hd) * SEQ + s0 + tx] = tile[tx][hd];
    }
}

// ---- kernel 5: flash attention ---------------------------------------
__global__ __launch_bounds__(256) void k_attn(const u16* __restrict__ qkv,
                                              const u16* __restrict__ Vt,
                                              u16* __restrict__ O) {
    __shared__ __align__(16) u16 Ks[64 * 64];
    __shared__ __align__(16) u16 Vs[64 * 64];
    __shared__ __align__(16) u16 Ps[4][16 * 64];
    const int bh = blockIdx.y;
    const int b = bh >> 4, h = bh & 15;
    const int q0 = blockIdx.x * 64;
    const int tid = threadIdx.x, wid = tid >> 6, lane = tid & 63;
    const int r = lane & 15, g = lane >> 4;
    const int srow = lane >> 3, scol = (lane & 7) * 8;
    const int qrow = q0 + wid * 16 + r;
    bf16x8 qf[2];
    qf[0] = *(const bf16x8*)&qkv[(size_t)(b * SEQ + qrow) * QKV_N + h * HDIM + g * 8];
    qf[1] = *(const bf16x8*)&qkv[(size_t)(b * SEQ + qrow) * QKV_N + h * HDIM + 32 + g * 8];
    float m_run[4], l_run[4];
    f32x4 oacc[4] = {};
#pragma unroll
    for (int e = 0; e < 4; ++e) { m_run[e] = -1e30f; l_run[e] = 0.f; }

    for (int sk0 = 0; sk0 < SEQ; sk0 += 64) {
#pragma unroll
        for (int i = 0; i < 2; ++i) {
            const int li = wid * 2 + i;
            const int row = li * 8 + srow;
            gl_lds16(&qkv[(size_t)(b * SEQ + sk0 + row) * QKV_N + DMODEL + h * HDIM + scol],
                     &Ks[li * 512]);
            gl_lds16(&Vt[((size_t)bh * HDIM + row) * SEQ + sk0 + scol], &Vs[li * 512]);
        }
        __syncthreads();
        // QK^T: rows=q (16 per wave), cols=s_k (64)
        f32x4 sacc[4] = {};
#pragma unroll
        for (int nf = 0; nf < 4; ++nf)
#pragma unroll
            for (int kk = 0; kk < 2; ++kk) {
                bf16x8 kf = *(const bf16x8*)&Ks[(nf * 16 + r) * 64 + kk * 32 + g * 8];
                sacc[nf] = __builtin_amdgcn_mfma_f32_16x16x32_bf16(qf[kk], kf, sacc[nf], 0, 0, 0);
            }
        // online softmax over this 64-col tile
        u16 pb[16];
#pragma unroll
        for (int e = 0; e < 4; ++e) {
            float mt = fmaxf(fmaxf(sacc[0][e], sacc[1][e]), fmaxf(sacc[2][e], sacc[3][e]));
#pragma unroll
            for (int d = 1; d < 16; d <<= 1) mt = fmaxf(mt, __shfl_xor(mt, d, 64));
            float mn = fmaxf(m_run[e], mt * ATT_SCALE);
            float al = exp2f((m_run[e] - mn) * L2E);
            m_run[e] = mn;
            float ls = 0.f;
#pragma unroll
            for (int nf = 0; nf < 4; ++nf) {
                float p = exp2f((sacc[nf][e] * ATT_SCALE - mn) * L2E);
                ls += p;
                pb[nf * 4 + e] = f2b(p);
            }
#pragma unroll
            for (int d = 1; d < 16; d <<= 1) ls += __shfl_xor(ls, d, 64);
            l_run[e] = l_run[e] * al + ls;
#pragma unroll
            for (int nf = 0; nf < 4; ++nf) oacc[nf][e] *= al;
        }
        // transpose P through per-wave LDS into A-fragment layout
        u16* ps = &Ps[wid][0];
#pragma unroll
        for (int nf = 0; nf < 4; ++nf)
#pragma unroll
            for (int e = 0; e < 4; ++e)
                ps[(g * 4 + e) * 64 + nf * 16 + r] = pb[nf * 4 + e];
        bf16x8 pf0 = *(const bf16x8*)&ps[r * 64 + g * 8];
        bf16x8 pf1 = *(const bf16x8*)&ps[r * 64 + 32 + g * 8];
        // PV: contract over s_k (64)
#pragma unroll
        for (int nf = 0; nf < 4; ++nf) {
            bf16x8 vf0 = *(const bf16x8*)&Vs[(nf * 16 + r) * 64 + g * 8];
            bf16x8 vf1 = *(const bf16x8*)&Vs[(nf * 16 + r) * 64 + 32 + g * 8];
            oacc[nf] = __builtin_amdgcn_mfma_f32_16x16x32_bf16(pf0, vf0, oacc[nf], 0, 0, 0);
            oacc[nf] = __builtin_amdgcn_mfma_f32_16x16x32_bf16(pf1, vf1, oacc[nf], 0, 0, 0);
        }
        __syncthreads();
    }
#pragma unroll
    for (int nf = 0; nf < 4; ++nf)
#pragma unroll
        for (int e = 0; e < 4; ++e) {
            float v = oacc[nf][e] / l_run[e];
            O[(size_t)(b * SEQ + q0 + wid * 16 + g * 4 + e) * DMODEL + h * HDIM + nf * 16 + r] =
                f2b(v);
        }
}

// ---- launcher --------------------------------------------------------
extern "C" void kernel_launch(void* const* d_in, const int* in_sizes, int n_in,
                              void* d_out, int out_size, void* d_ws, size_t ws_size,
                              hipStream_t stream) {
    const float* x = (const float*)d_in[0];
    const float* Wqkv = (const float*)d_in[1];
    const float* Wproj = (const float*)d_in[2];
    float* out = (float*)d_out;

    u16* xb = (u16*)d_ws;                                  //  8 MB
    u16* WqkvT = xb + (size_t)MTOT * DMODEL;               //  6 MB
    u16* WprojT = WqkvT + (size_t)QKV_N * DMODEL;          //  2 MB
    u16* qkv = WprojT + (size_t)DMODEL * DMODEL;           // 24 MB
    u16* Vt = qkv + (size_t)MTOT * QKV_N;                  //  8 MB
    u16* Ob = Vt + (size_t)BATCH * NH * HDIM * SEQ;        //  8 MB

    k_cvt<<<dim3((MTOT * DMODEL / 8) / 256), 256, 0, stream>>>(x, xb, MTOT * DMODEL / 8);
    k_wtrans<<<dim3(QKV_N / 64, DMODEL / 64), 256, 0, stream>>>(Wqkv, WqkvT, DMODEL, QKV_N);
    k_wtrans<<<dim3(DMODEL / 64, DMODEL / 64), 256, 0, stream>>>(Wproj, WprojT, DMODEL, DMODEL);
    k_gemm_bt<false><<<dim3(QKV_N / 128, MTOT / 128), 256, 0, stream>>>(
        xb, WqkvT, (void*)qkv, MTOT, QKV_N, DMODEL);
    k_vtrans<<<dim3(SEQ / 64, BATCH * NH), 256, 0, stream>>>(qkv, Vt);
    k_attn<<<dim3(SEQ / 64, BATCH * NH), 256, 0, stream>>>(qkv, Vt, Ob);
    k_gemm_bt<true><<<dim3(DMODEL / 128, MTOT / 128), 256, 0, stream>>>(
        Ob, WprojT, (void*)out, MTOT, DMODEL, DMODEL);
}

// Round 2
// 244.364 us; speedup vs baseline: 1.2829x; 1.2829x over previous
//
#include <hip/hip_runtime.h>
#include <stdint.h>

typedef unsigned short u16;
typedef __attribute__((ext_vector_type(8))) short bf16x8;
typedef __attribute__((ext_vector_type(4))) float f32x4;

#define BATCH 2
#define SEQ 2048
#define NH 16
#define HDIM 64
#define DMODEL 1024
#define MTOT (BATCH * SEQ)      // 4096
#define QKV_N (3 * DMODEL)      // 3072
#define ATT_SCALE 0.125f
#define L2E 1.44269504088896340736f
#define C2 (ATT_SCALE * L2E)

// ---- helpers ----------------------------------------------------------
__device__ __forceinline__ u16 f2b(float f) {   // fp32 -> bf16 (RNE)
    uint32_t x = __builtin_bit_cast(uint32_t, f);
    uint32_t r = (x + 0x7fffu + ((x >> 16) & 1u)) >> 16;
    return (u16)r;
}

__device__ __forceinline__ void gl_lds16(const void* g, void* l) {
    // async global->LDS, 16B per lane; LDS dest is wave-uniform base + lane*16
    __builtin_amdgcn_global_load_lds(
        (const __attribute__((address_space(1))) void*)g,
        (__attribute__((address_space(3))) void*)l, 16, 0, 0);
}

// ---- kernel 1: fp32 -> bf16 elementwise ------------------------------
__global__ __launch_bounds__(256) void k_cvt(const float* __restrict__ in,
                                             u16* __restrict__ out, int n8) {
    int i = blockIdx.x * blockDim.x + threadIdx.x;
    if (i >= n8) return;
    const float4* p = (const float4*)in + (size_t)i * 2;
    float4 a = p[0], b = p[1];
    union { u16 t[8]; uint4 v; } u;
    u.t[0] = f2b(a.x); u.t[1] = f2b(a.y); u.t[2] = f2b(a.z); u.t[3] = f2b(a.w);
    u.t[4] = f2b(b.x); u.t[5] = f2b(b.y); u.t[6] = f2b(b.z); u.t[7] = f2b(b.w);
    *(uint4*)(out + (size_t)i * 8) = u.v;
}

// ---- kernel 2: W[rows][cols] fp32 -> WT[cols][rows] bf16 -------------
__global__ __launch_bounds__(256) void k_wtrans(const float* __restrict__ W,
                                                u16* __restrict__ WT,
                                                int rows, int cols) {
    __shared__ float tile[64][65];
    const int c0 = blockIdx.x * 64, r0 = blockIdx.y * 64;
    const int tx = threadIdx.x & 63, ty = threadIdx.x >> 6;
#pragma unroll
    for (int i = 0; i < 16; ++i) {
        int r = i * 4 + ty;
        tile[r][tx] = W[(size_t)(r0 + r) * cols + c0 + tx];
    }
    __syncthreads();
#pragma unroll
    for (int i = 0; i < 16; ++i) {
        int c = i * 4 + ty;
        WT[(size_t)(c0 + c) * rows + r0 + tx] = f2b(tile[tx][c]);
    }
}

// ---- kernel 3/6: C[M,N] = A[M,K] * BT[N,K]^T  (bf16 in, bf16/f32 out)
template <bool F32OUT>
__global__ __launch_bounds__(256) void k_gemm_bt(const u16* __restrict__ A,
                                                 const u16* __restrict__ BT,
                                                 void* __restrict__ C,
                                                 int M, int N, int K) {
    __shared__ __align__(16) u16 As[128 * 64];
    __shared__ __align__(16) u16 Bs[128 * 64];
    const int tid = threadIdx.x;
    const int wid = tid >> 6, lane = tid & 63;
    const int r = lane & 15, g = lane >> 4;
    const int m0 = blockIdx.y * 128, n0 = blockIdx.x * 128;
    const int wm = (wid >> 1) * 64, wn = (wid & 1) * 64;
    const int srow = lane >> 3, scol = (lane & 7) * 8;
    f32x4 acc[4][4] = {};
    for (int k0 = 0; k0 < K; k0 += 64) {
#pragma unroll
        for (int i = 0; i < 4; ++i) {
            const int li = wid * 4 + i;
            gl_lds16(A + (size_t)(m0 + li * 8 + srow) * K + k0 + scol, &As[li * 512]);
            gl_lds16(BT + (size_t)(n0 + li * 8 + srow) * K + k0 + scol, &Bs[li * 512]);
        }
        __syncthreads();
#pragma unroll
        for (int kk = 0; kk < 2; ++kk) {
            bf16x8 af[4], bfr[4];
#pragma unroll
            for (int mi = 0; mi < 4; ++mi)
                af[mi] = *(const bf16x8*)&As[(wm + mi * 16 + r) * 64 + kk * 32 + g * 8];
#pragma unroll
            for (int ni = 0; ni < 4; ++ni)
                bfr[ni] = *(const bf16x8*)&Bs[(wn + ni * 16 + r) * 64 + kk * 32 + g * 8];
#pragma unroll
            for (int mi = 0; mi < 4; ++mi)
#pragma unroll
                for (int ni = 0; ni < 4; ++ni)
                    acc[mi][ni] = __builtin_amdgcn_mfma_f32_16x16x32_bf16(
                        af[mi], bfr[ni], acc[mi][ni], 0, 0, 0);
        }
        __syncthreads();
    }
#pragma unroll
    for (int mi = 0; mi < 4; ++mi)
#pragma unroll
        for (int ni = 0; ni < 4; ++ni) {
            const int col = n0 + wn + ni * 16 + r;
#pragma unroll
            for (int e = 0; e < 4; ++e) {
                const int row = m0 + wm + mi * 16 + g * 4 + e;
                if (F32OUT)
                    ((float*)C)[(size_t)row * N + col] = acc[mi][ni][e];
                else
                    ((u16*)C)[(size_t)row * N + col] = f2b(acc[mi][ni][e]);
            }
        }
}

// ---- kernel 4: Vt[b][h][hd][s] <- qkv V slice ------------------------
__global__ __launch_bounds__(256) void k_vtrans(const u16* __restrict__ qkv,
                                                u16* __restrict__ Vt) {
    __shared__ u16 tile[64][65];
    const int bh = blockIdx.y;
    const int b = bh >> 4, h = bh & 15;
    const int s0 = blockIdx.x * 64;
    const int tx = threadIdx.x & 63, ty = threadIdx.x >> 6;
#pragma unroll
    for (int i = 0; i < 16; ++i) {
        int s = i * 4 + ty;
        tile[s][tx] = qkv[(size_t)(b * SEQ + s0 + s) * QKV_N + 2 * DMODEL + h * HDIM + tx];
    }
    __syncthreads();
#pragma unroll
    for (int i = 0; i < 16; ++i) {
        int hd = i * 4 + ty;
        Vt[((size_t)bh * HDIM + hd) * SEQ + s0 + tx] = tile[tx][hd];
    }
}

// ---- kernel 5: flash attention v2 ------------------------------------
// Swapped QK^T (S^T), in-register softmax (q = lane&15), zero-exchange PV.
//
// K LDS layout (elem): f = (s>>5)*2048 + (d>>5)*1024 + ((s>>2)&1)*512
//                        + ((s>>3)&3)*128 + (s&3)*32 + ((d>>3)&3)*8 + (d&7)
//   -> per (nf,kk) ds_read_b128: 64 lanes read 1024 contiguous B, 0 conflicts.
// V LDS layout (elem): f = ((s>>5)*4 + (hd>>4))*512 + ((s>>3)&3)*128
//                        + (hd&15)*8 + (s&7)
//   -> per (half,ht) ds_read_b128: 64 lanes read 1024 contiguous B, 0 conflicts.
// Both layouts are staged by global_load_lds with 16B-contiguous global sources.
__global__ __launch_bounds__(256) void k_attn(const u16* __restrict__ qkv,
                                              const u16* __restrict__ Vt,
                                              u16* __restrict__ O) {
    __shared__ __align__(16) u16 Ks[4096];
    __shared__ __align__(16) u16 Vs[4096];
    const int bh = blockIdx.y;
    const int b = bh >> 4, h = bh & 15;
    const int q0 = blockIdx.x * 64;
    const int tid = threadIdx.x, wid = tid >> 6, lane = tid & 63;
    const int r = lane & 15, g = lane >> 4;

    // Q fragment (B-operand of swapped QK^T): lane's q-row = r
    const size_t qbase = (size_t)(b * SEQ + q0 + wid * 16 + r) * QKV_N + h * HDIM;
    const bf16x8 qf0 = *(const bf16x8*)&qkv[qbase + g * 8];
    const bf16x8 qf1 = *(const bf16x8*)&qkv[qbase + 32 + g * 8];

    float mL = -1e30f, lsum = 0.f;
    f32x4 oacc[4] = {};

    // staging source offsets (per wave: calls kc = 2*wid, 2*wid+1)
    const int kc0 = wid * 2;
    // K source: row = (kc>>2)*32 + g*8 + (kc&1)*4 + ((lane>>2)&3), col = ((kc>>1)&1)*32 + (lane&3)*8
    // V source: hd = (kc&3)*16 + r, s-col = (kc>>2)*32 + g*8

    for (int sk0 = 0; sk0 < SEQ; sk0 += 64) {
#pragma unroll
        for (int i = 0; i < 2; ++i) {
            const int kc = kc0 + i;
            const int ksrow = (kc >> 2) * 32 + g * 8 + (kc & 1) * 4 + ((lane >> 2) & 3);
            const int kscol = ((kc >> 1) & 1) * 32 + (lane & 3) * 8;
            gl_lds16(&qkv[(size_t)(b * SEQ + sk0 + ksrow) * QKV_N + DMODEL + h * HDIM + kscol],
                     &Ks[kc * 512]);
            const int vhd = (kc & 3) * 16 + r;
            const int vsc = (kc >> 2) * 32 + g * 8;
            gl_lds16(&Vt[((size_t)bh * HDIM + vhd) * SEQ + sk0 + vsc], &Vs[kc * 512]);
        }
        __syncthreads();

        // QK^T (swapped): sacc[nf][e] = S^T[k = (nf&1)*32 + g*8 + (nf>>1)*4 + e][q=r]
        f32x4 sacc[4] = {};
#pragma unroll
        for (int nf = 0; nf < 4; ++nf) {
            const int kbase = (nf & 1) * 2048 + (nf >> 1) * 512 +
                              (r >> 2) * 128 + (r & 3) * 32 + g * 8;
            bf16x8 kf0 = *(const bf16x8*)&Ks[kbase];
            bf16x8 kf1 = *(const bf16x8*)&Ks[kbase + 1024];
            sacc[nf] = __builtin_amdgcn_mfma_f32_16x16x32_bf16(kf0, qf0, sacc[nf], 0, 0, 0);
            sacc[nf] = __builtin_amdgcn_mfma_f32_16x16x32_bf16(kf1, qf1, sacc[nf], 0, 0, 0);
        }

        // online softmax, fully in-register (per-lane q = r)
        float mt = sacc[0][0];
#pragma unroll
        for (int nf = 0; nf < 4; ++nf)
#pragma unroll
            for (int e = 0; e < 4; ++e) mt = fmaxf(mt, sacc[nf][e]);
        mt = fmaxf(mt, __shfl_xor(mt, 16, 64));
        mt = fmaxf(mt, __shfl_xor(mt, 32, 64));
        const float mNew = fmaxf(mL, mt * C2);
        const float al = exp2f(mL - mNew);
        mL = mNew;
        float p[4][4];
        float ls = 0.f;
#pragma unroll
        for (int nf = 0; nf < 4; ++nf)
#pragma unroll
            for (int e = 0; e < 4; ++e) {
                p[nf][e] = exp2f(sacc[nf][e] * C2 - mNew);
                ls += p[nf][e];
            }
        ls += __shfl_xor(ls, 16, 64);
        ls += __shfl_xor(ls, 32, 64);
        lsum = lsum * al + ls;
#pragma unroll
        for (int ht = 0; ht < 4; ++ht)
#pragma unroll
            for (int e = 0; e < 4; ++e) oacc[ht][e] *= al;

        // pack P^T B-fragments: pf[half] elem j <- k = half*32 + g*8 + j
        //   (nf = half + 2*(j>>2), e = j&3)
        union { u16 t[8]; bf16x8 v; } upf0, upf1;
#pragma unroll
        for (int e = 0; e < 4; ++e) {
            upf0.t[e] = f2b(p[0][e]);
            upf0.t[4 + e] = f2b(p[2][e]);
            upf1.t[e] = f2b(p[1][e]);
            upf1.t[4 + e] = f2b(p[3][e]);
        }

        // PV: O^T = V^T * P^T ; oacc[ht] holds O[q=r][hd=ht*16+g*4+e]
#pragma unroll
        for (int ht = 0; ht < 4; ++ht) {
            bf16x8 vf0 = *(const bf16x8*)&Vs[ht * 512 + g * 128 + r * 8];
            bf16x8 vf1 = *(const bf16x8*)&Vs[(4 + ht) * 512 + g * 128 + r * 8];
            oacc[ht] = __builtin_amdgcn_mfma_f32_16x16x32_bf16(vf0, upf0.v, oacc[ht], 0, 0, 0);
            oacc[ht] = __builtin_amdgcn_mfma_f32_16x16x32_bf16(vf1, upf1.v, oacc[ht], 0, 0, 0);
        }
        __syncthreads();
    }

    const float inv = 1.0f / lsum;
    const size_t obase = (size_t)(b * SEQ + q0 + wid * 16 + r) * DMODEL + h * HDIM;
#pragma unroll
    for (int ht = 0; ht < 4; ++ht) {
        union { u16 t[4]; ushort4 v; } o;
#pragma unroll
        for (int e = 0; e < 4; ++e) o.t[e] = f2b(oacc[ht][e] * inv);
        *(ushort4*)&O[obase + ht * 16 + g * 4] = o.v;
    }
}

// ---- launcher --------------------------------------------------------
extern "C" void kernel_launch(void* const* d_in, const int* in_sizes, int n_in,
                              void* d_out, int out_size, void* d_ws, size_t ws_size,
                              hipStream_t stream) {
    const float* x = (const float*)d_in[0];
    const float* Wqkv = (const float*)d_in[1];
    const float* Wproj = (const float*)d_in[2];
    float* out = (float*)d_out;

    u16* xb = (u16*)d_ws;                                  //  8 MB
    u16* WqkvT = xb + (size_t)MTOT * DMODEL;               //  6 MB
    u16* WprojT = WqkvT + (size_t)QKV_N * DMODEL;          //  2 MB
    u16* qkv = WprojT + (size_t)DMODEL * DMODEL;           // 24 MB
    u16* Vt = qkv + (size_t)MTOT * QKV_N;                  //  8 MB
    u16* Ob = Vt + (size_t)BATCH * NH * HDIM * SEQ;        //  8 MB

    k_cvt<<<dim3((MTOT * DMODEL / 8) / 256), 256, 0, stream>>>(x, xb, MTOT * DMODEL / 8);
    k_wtrans<<<dim3(QKV_N / 64, DMODEL / 64), 256, 0, stream>>>(Wqkv, WqkvT, DMODEL, QKV_N);
    k_wtrans<<<dim3(DMODEL / 64, DMODEL / 64), 256, 0, stream>>>(Wproj, WprojT, DMODEL, DMODEL);
    k_gemm_bt<false><<<dim3(QKV_N / 128, MTOT / 128), 256, 0, stream>>>(
        xb, WqkvT, (void*)qkv, MTOT, QKV_N, DMODEL);
    k_vtrans<<<dim3(SEQ / 64, BATCH * NH), 256, 0, stream>>>(qkv, Vt);
    k_attn<<<dim3(SEQ / 64, BATCH * NH), 256, 0, stream>>>(qkv, Vt, Ob);
    k_gemm_bt<true><<<dim3(DMODEL / 128, MTOT / 128), 256, 0, stream>>>(
        Ob, WprojT, (void*)out, MTOT, DMODEL, DMODEL);
}

// Round 3
// 243.034 us; speedup vs baseline: 1.2899x; 1.0055x over previous
//
#include <hip/hip_runtime.h>
#include <stdint.h>

typedef unsigned short u16;
typedef __attribute__((ext_vector_type(8))) short bf16x8;
typedef __attribute__((ext_vector_type(4))) float f32x4;

#define BATCH 2
#define SEQ 2048
#define NH 16
#define HDIM 64
#define DMODEL 1024
#define MTOT (BATCH * SEQ)      // 4096
#define QKV_N (3 * DMODEL)      // 3072
#define ATT_SCALE 0.125f
#define L2E 1.44269504088896340736f
#define C2 (ATT_SCALE * L2E)

// ---- helpers ----------------------------------------------------------
__device__ __forceinline__ u16 f2b(float f) {   // fp32 -> bf16 (RNE)
    uint32_t x = __builtin_bit_cast(uint32_t, f);
    uint32_t r = (x + 0x7fffu + ((x >> 16) & 1u)) >> 16;
    return (u16)r;
}

__device__ __forceinline__ uint32_t cvt_pk(float lo, float hi) {
    // dst[15:0] = bf16(lo), dst[31:16] = bf16(hi)
    uint32_t r;
    asm("v_cvt_pk_bf16_f32 %0, %1, %2" : "=v"(r) : "v"(lo), "v"(hi));
    return r;
}

__device__ __forceinline__ void gl_lds16(const void* g, void* l) {
    // async global->LDS, 16B per lane; LDS dest is wave-uniform base + lane*16
    __builtin_amdgcn_global_load_lds(
        (const __attribute__((address_space(1))) void*)g,
        (__attribute__((address_space(3))) void*)l, 16, 0, 0);
}

// ---- kernel 1: fp32 -> bf16 elementwise ------------------------------
__global__ __launch_bounds__(256) void k_cvt(const float* __restrict__ in,
                                             u16* __restrict__ out, int n8) {
    int i = blockIdx.x * blockDim.x + threadIdx.x;
    if (i >= n8) return;
    const float4* p = (const float4*)in + (size_t)i * 2;
    float4 a = p[0], b = p[1];
    union { uint32_t w[4]; uint4 v; } u;
    u.w[0] = cvt_pk(a.x, a.y);
    u.w[1] = cvt_pk(a.z, a.w);
    u.w[2] = cvt_pk(b.x, b.y);
    u.w[3] = cvt_pk(b.z, b.w);
    *(uint4*)(out + (size_t)i * 8) = u.v;
}

// ---- kernel 2: W[rows][cols] fp32 -> WT[cols][rows] bf16 -------------
__global__ __launch_bounds__(256) void k_wtrans(const float* __restrict__ W,
                                                u16* __restrict__ WT,
                                                int rows, int cols) {
    __shared__ float tile[64][65];
    const int c0 = blockIdx.x * 64, r0 = blockIdx.y * 64;
    const int tx = threadIdx.x & 63, ty = threadIdx.x >> 6;
#pragma unroll
    for (int i = 0; i < 16; ++i) {
        int r = i * 4 + ty;
        tile[r][tx] = W[(size_t)(r0 + r) * cols + c0 + tx];
    }
    __syncthreads();
#pragma unroll
    for (int i = 0; i < 16; ++i) {
        int c = i * 4 + ty;
        WT[(size_t)(c0 + c) * rows + r0 + tx] = f2b(tile[tx][c]);
    }
}

// ---- kernel 3/6: C[M,N] = A[M,K] * BT[N,K]^T  (bf16 in, bf16/f32 out)
// MFMA operand order (B-frag, A-frag): lane (r,g) reg e = C[row=r][col=g*4+e]
// within each 16x16 fragment -> vectorized 8B/16B epilogue stores.
template <bool F32OUT>
__global__ __launch_bounds__(256) void k_gemm_bt(const u16* __restrict__ A,
                                                 const u16* __restrict__ BT,
                                                 void* __restrict__ C,
                                                 int M, int N, int K) {
    __shared__ __align__(16) u16 As[128 * 64];
    __shared__ __align__(16) u16 Bs[128 * 64];
    const int tid = threadIdx.x;
    const int wid = tid >> 6, lane = tid & 63;
    const int r = lane & 15, g = lane >> 4;
    const int m0 = blockIdx.y * 128, n0 = blockIdx.x * 128;
    const int wm = (wid >> 1) * 64, wn = (wid & 1) * 64;
    const int srow = lane >> 3, scol = (lane & 7) * 8;
    f32x4 acc[4][4] = {};
    for (int k0 = 0; k0 < K; k0 += 64) {
#pragma unroll
        for (int i = 0; i < 4; ++i) {
            const int li = wid * 4 + i;
            gl_lds16(A + (size_t)(m0 + li * 8 + srow) * K + k0 + scol, &As[li * 512]);
            gl_lds16(BT + (size_t)(n0 + li * 8 + srow) * K + k0 + scol, &Bs[li * 512]);
        }
        __syncthreads();
#pragma unroll
        for (int kk = 0; kk < 2; ++kk) {
            bf16x8 af[4], bfr[4];
#pragma unroll
            for (int mi = 0; mi < 4; ++mi)
                af[mi] = *(const bf16x8*)&As[(wm + mi * 16 + r) * 64 + kk * 32 + g * 8];
#pragma unroll
            for (int ni = 0; ni < 4; ++ni)
                bfr[ni] = *(const bf16x8*)&Bs[(wn + ni * 16 + r) * 64 + kk * 32 + g * 8];
#pragma unroll
            for (int mi = 0; mi < 4; ++mi)
#pragma unroll
                for (int ni = 0; ni < 4; ++ni)
                    acc[mi][ni] = __builtin_amdgcn_mfma_f32_16x16x32_bf16(
                        bfr[ni], af[mi], acc[mi][ni], 0, 0, 0);
        }
        __syncthreads();
    }
#pragma unroll
    for (int mi = 0; mi < 4; ++mi)
#pragma unroll
        for (int ni = 0; ni < 4; ++ni) {
            const int row = m0 + wm + mi * 16 + r;
            const int col = n0 + wn + ni * 16 + g * 4;
            if (F32OUT) {
                float4 vv;
                vv.x = acc[mi][ni][0]; vv.y = acc[mi][ni][1];
                vv.z = acc[mi][ni][2]; vv.w = acc[mi][ni][3];
                *(float4*)&((float*)C)[(size_t)row * N + col] = vv;
            } else {
                union { uint32_t w[2]; ushort4 v; } o;
                o.w[0] = cvt_pk(acc[mi][ni][0], acc[mi][ni][1]);
                o.w[1] = cvt_pk(acc[mi][ni][2], acc[mi][ni][3]);
                *(ushort4*)&((u16*)C)[(size_t)row * N + col] = o.v;
            }
        }
}

// ---- kernel 4: Vt[b][h][hd][s] <- qkv V slice ------------------------
__global__ __launch_bounds__(256) void k_vtrans(const u16* __restrict__ qkv,
                                                u16* __restrict__ Vt) {
    __shared__ u16 tile[64][65];
    const int bh = blockIdx.y;
    const int b = bh >> 4, h = bh & 15;
    const int s0 = blockIdx.x * 64;
    const int tx = threadIdx.x & 63, ty = threadIdx.x >> 6;
#pragma unroll
    for (int i = 0; i < 16; ++i) {
        int s = i * 4 + ty;
        tile[s][tx] = qkv[(size_t)(b * SEQ + s0 + s) * QKV_N + 2 * DMODEL + h * HDIM + tx];
    }
    __syncthreads();
#pragma unroll
    for (int i = 0; i < 16; ++i) {
        int hd = i * 4 + ty;
        Vt[((size_t)bh * HDIM + hd) * SEQ + s0 + tx] = tile[tx][hd];
    }
}

// ---- kernel 5: flash attention v3 ------------------------------------
// Swapped QK^T (S^T), in-register softmax (q = lane&15), zero-exchange PV,
// 2-phase double-buffered staging (one barrier per tile), defer-max,
// cvt_pk packing, deferred l-sum reduction.
__global__ __launch_bounds__(256) void k_attn(const u16* __restrict__ qkv,
                                              const u16* __restrict__ Vt,
                                              u16* __restrict__ O) {
    __shared__ __align__(16) u16 Ks[2][4096];
    __shared__ __align__(16) u16 Vs[2][4096];
    const int bh = blockIdx.y;
    const int b = bh >> 4, h = bh & 15;
    const int q0 = blockIdx.x * 64;
    const int tid = threadIdx.x, wid = tid >> 6, lane = tid & 63;
    const int r = lane & 15, g = lane >> 4;

    // Q fragment (second operand of swapped QK^T): lane's q-row = r
    const size_t qbase = (size_t)(b * SEQ + q0 + wid * 16 + r) * QKV_N + h * HDIM;
    const bf16x8 qf0 = *(const bf16x8*)&qkv[qbase + g * 8];
    const bf16x8 qf1 = *(const bf16x8*)&qkv[qbase + 32 + g * 8];

    float mL = -1e30f, lsum = 0.f;
    f32x4 oacc[4] = {};

    const int kc0 = wid * 2;
    // staging address components (per kc = 0..7):
    //   K: row = (kc>>2)*32 + g*8 + (kc&1)*4 + ((lane>>2)&3), col = ((kc>>1)&1)*32 + (lane&3)*8
    //   V: hd  = (kc&3)*16 + r,                         s-col = (kc>>2)*32 + g*8

#define STAGE(BUF, SK0)                                                          \
    {                                                                            \
        _Pragma("unroll") for (int i = 0; i < 2; ++i) {                          \
            const int kc = kc0 + i;                                              \
            const int ksrow = (kc >> 2) * 32 + g * 8 + (kc & 1) * 4 + ((lane >> 2) & 3); \
            const int kscol = ((kc >> 1) & 1) * 32 + (lane & 3) * 8;             \
            gl_lds16(&qkv[(size_t)(b * SEQ + (SK0) + ksrow) * QKV_N + DMODEL +   \
                          h * HDIM + kscol],                                     \
                     &Ks[BUF][kc * 512]);                                        \
            const int vhd = (kc & 3) * 16 + r;                                   \
            const int vsc = (kc >> 2) * 32 + g * 8;                              \
            gl_lds16(&Vt[((size_t)bh * HDIM + vhd) * SEQ + (SK0) + vsc],         \
                     &Vs[BUF][kc * 512]);                                        \
        }                                                                        \
    }

    STAGE(0, 0);
    asm volatile("s_waitcnt vmcnt(0)");
    __syncthreads();

    for (int t = 0; t < SEQ / 64; ++t) {
        const int cur = t & 1;
        if (t < SEQ / 64 - 1) STAGE(cur ^ 1, (t + 1) * 64);

        // QK^T (swapped): sacc[nf][e] = S^T[k=(nf&1)*32+g*8+(nf>>1)*4+e][q=r]
        f32x4 sacc[4] = {};
        __builtin_amdgcn_s_setprio(1);
#pragma unroll
        for (int nf = 0; nf < 4; ++nf) {
            const int kbase = (nf & 1) * 2048 + (nf >> 1) * 512 +
                              (r >> 2) * 128 + (r & 3) * 32 + g * 8;
            bf16x8 kf0 = *(const bf16x8*)&Ks[cur][kbase];
            bf16x8 kf1 = *(const bf16x8*)&Ks[cur][kbase + 1024];
            sacc[nf] = __builtin_amdgcn_mfma_f32_16x16x32_bf16(kf0, qf0, sacc[nf], 0, 0, 0);
            sacc[nf] = __builtin_amdgcn_mfma_f32_16x16x32_bf16(kf1, qf1, sacc[nf], 0, 0, 0);
        }
        __builtin_amdgcn_s_setprio(0);

        // online softmax, in-register (per-lane q = r), deferred l-reduce
        float mt = fmaxf(fmaxf(sacc[0][0], sacc[0][1]), fmaxf(sacc[0][2], sacc[0][3]));
#pragma unroll
        for (int nf = 1; nf < 4; ++nf)
            mt = fmaxf(mt, fmaxf(fmaxf(sacc[nf][0], sacc[nf][1]),
                                 fmaxf(sacc[nf][2], sacc[nf][3])));
        mt = fmaxf(mt, __shfl_xor(mt, 16, 64));
        mt = fmaxf(mt, __shfl_xor(mt, 32, 64));
        const float pm = mt * C2;
        if (!__all(pm - mL <= 8.f)) {     // defer-max: rescale only on real growth
            const float mNew = fmaxf(mL, pm);
            const float al = exp2f(mL - mNew);
            mL = mNew;
            lsum *= al;
#pragma unroll
            for (int ht = 0; ht < 4; ++ht)
#pragma unroll
                for (int e = 0; e < 4; ++e) oacc[ht][e] *= al;
        }
        float p[4][4];
#pragma unroll
        for (int nf = 0; nf < 4; ++nf)
#pragma unroll
            for (int e = 0; e < 4; ++e) {
                p[nf][e] = exp2f(sacc[nf][e] * C2 - mL);
                lsum += p[nf][e];
            }

        // pack P^T fragments: pf[half] elem j <- k = half*32 + g*8 + j
        union { uint32_t w[4]; bf16x8 v; } upf0, upf1;
        upf0.w[0] = cvt_pk(p[0][0], p[0][1]);
        upf0.w[1] = cvt_pk(p[0][2], p[0][3]);
        upf0.w[2] = cvt_pk(p[2][0], p[2][1]);
        upf0.w[3] = cvt_pk(p[2][2], p[2][3]);
        upf1.w[0] = cvt_pk(p[1][0], p[1][1]);
        upf1.w[1] = cvt_pk(p[1][2], p[1][3]);
        upf1.w[2] = cvt_pk(p[3][0], p[3][1]);
        upf1.w[3] = cvt_pk(p[3][2], p[3][3]);

        // PV: O^T = V^T * P^T ; oacc[ht] holds O[q=r][hd=ht*16+g*4+e]
        __builtin_amdgcn_s_setprio(1);
#pragma unroll
        for (int ht = 0; ht < 4; ++ht) {
            bf16x8 vf0 = *(const bf16x8*)&Vs[cur][ht * 512 + g * 128 + r * 8];
            bf16x8 vf1 = *(const bf16x8*)&Vs[cur][(4 + ht) * 512 + g * 128 + r * 8];
            oacc[ht] = __builtin_amdgcn_mfma_f32_16x16x32_bf16(vf0, upf0.v, oacc[ht], 0, 0, 0);
            oacc[ht] = __builtin_amdgcn_mfma_f32_16x16x32_bf16(vf1, upf1.v, oacc[ht], 0, 0, 0);
        }
        __builtin_amdgcn_s_setprio(0);

        asm volatile("s_waitcnt vmcnt(0)");
        __syncthreads();
    }
#undef STAGE

    // epilogue: finish deferred l-reduction across the 4-lane q-row group
    lsum += __shfl_xor(lsum, 16, 64);
    lsum += __shfl_xor(lsum, 32, 64);
    const float inv = 1.0f / lsum;
    const size_t obase = (size_t)(b * SEQ + q0 + wid * 16 + r) * DMODEL + h * HDIM;
#pragma unroll
    for (int ht = 0; ht < 4; ++ht) {
        union { uint32_t w[2]; ushort4 v; } o;
        o.w[0] = cvt_pk(oacc[ht][0] * inv, oacc[ht][1] * inv);
        o.w[1] = cvt_pk(oacc[ht][2] * inv, oacc[ht][3] * inv);
        *(ushort4*)&O[obase + ht * 16 + g * 4] = o.v;
    }
}

// ---- launcher --------------------------------------------------------
extern "C" void kernel_launch(void* const* d_in, const int* in_sizes, int n_in,
                              void* d_out, int out_size, void* d_ws, size_t ws_size,
                              hipStream_t stream) {
    const float* x = (const float*)d_in[0];
    const float* Wqkv = (const float*)d_in[1];
    const float* Wproj = (const float*)d_in[2];
    float* out = (float*)d_out;

    u16* xb = (u16*)d_ws;                                  //  8 MB
    u16* WqkvT = xb + (size_t)MTOT * DMODEL;               //  6 MB
    u16* WprojT = WqkvT + (size_t)QKV_N * DMODEL;          //  2 MB
    u16* qkv = WprojT + (size_t)DMODEL * DMODEL;           // 24 MB
    u16* Vt = qkv + (size_t)MTOT * QKV_N;                  //  8 MB
    u16* Ob = Vt + (size_t)BATCH * NH * HDIM * SEQ;        //  8 MB

    k_cvt<<<dim3((MTOT * DMODEL / 8) / 256), 256, 0, stream>>>(x, xb, MTOT * DMODEL / 8);
    k_wtrans<<<dim3(QKV_N / 64, DMODEL / 64), 256, 0, stream>>>(Wqkv, WqkvT, DMODEL, QKV_N);
    k_wtrans<<<dim3(DMODEL / 64, DMODEL / 64), 256, 0, stream>>>(Wproj, WprojT, DMODEL, DMODEL);
    k_gemm_bt<false><<<dim3(QKV_N / 128, MTOT / 128), 256, 0, stream>>>(
        xb, WqkvT, (void*)qkv, MTOT, QKV_N, DMODEL);
    k_vtrans<<<dim3(SEQ / 64, BATCH * NH), 256, 0, stream>>>(qkv, Vt);
    k_attn<<<dim3(SEQ / 64, BATCH * NH), 256, 0, stream>>>(qkv, Vt, Ob);
    k_gemm_bt<true><<<dim3(DMODEL / 128, MTOT / 128), 256, 0, stream>>>(
        Ob, WprojT, (void*)out, MTOT, DMODEL, DMODEL);
}

// Round 5
// 230.312 us; speedup vs baseline: 1.3611x; 1.0552x over previous
//
#include <hip/hip_runtime.h>
#include <stdint.h>

typedef unsigned short u16;
typedef __attribute__((ext_vector_type(8))) short bf16x8;
typedef __attribute__((ext_vector_type(4))) float f32x4;

#define BATCH 2
#define SEQ 2048
#define NH 16
#define HDIM 64
#define DMODEL 1024
#define MTOT (BATCH * SEQ)      // 4096
#define QKV_N (3 * DMODEL)      // 3072
#define ATT_SCALE 0.125f
#define L2E 1.44269504088896340736f
#define C2 (ATT_SCALE * L2E)

#define BAR() asm volatile("s_barrier" ::: "memory")

// ---- helpers ----------------------------------------------------------
__device__ __forceinline__ u16 f2b(float f) {   // fp32 -> bf16 (RNE)
    uint32_t x = __builtin_bit_cast(uint32_t, f);
    uint32_t r = (x + 0x7fffu + ((x >> 16) & 1u)) >> 16;
    return (u16)r;
}

__device__ __forceinline__ uint32_t cvt_pk(float lo, float hi) {
    uint32_t r;
    asm("v_cvt_pk_bf16_f32 %0, %1, %2" : "=v"(r) : "v"(lo), "v"(hi));
    return r;
}

__device__ __forceinline__ void gl_lds16(const void* g, void* l) {
    __builtin_amdgcn_global_load_lds(
        (const __attribute__((address_space(1))) void*)g,
        (__attribute__((address_space(3))) void*)l, 16, 0, 0);
}

// ---- kernel 1: fp32 -> bf16 elementwise ------------------------------
__global__ __launch_bounds__(256) void k_cvt(const float* __restrict__ in,
                                             u16* __restrict__ out, int n8) {
    int i = blockIdx.x * blockDim.x + threadIdx.x;
    if (i >= n8) return;
    const float4* p = (const float4*)in + (size_t)i * 2;
    float4 a = p[0], b = p[1];
    union { uint32_t w[4]; uint4 v; } u;
    u.w[0] = cvt_pk(a.x, a.y);
    u.w[1] = cvt_pk(a.z, a.w);
    u.w[2] = cvt_pk(b.x, b.y);
    u.w[3] = cvt_pk(b.z, b.w);
    *(uint4*)(out + (size_t)i * 8) = u.v;
}

// ---- kernel 2: W[rows][cols] fp32 -> WT[cols][rows] bf16 -------------
__global__ __launch_bounds__(256) void k_wtrans(const float* __restrict__ W,
                                                u16* __restrict__ WT,
                                                int rows, int cols) {
    __shared__ float tile[64][65];
    const int c0 = blockIdx.x * 64, r0 = blockIdx.y * 64;
    const int tx = threadIdx.x & 63, ty = threadIdx.x >> 6;
#pragma unroll
    for (int i = 0; i < 16; ++i) {
        int r = i * 4 + ty;
        tile[r][tx] = W[(size_t)(r0 + r) * cols + c0 + tx];
    }
    __syncthreads();
#pragma unroll
    for (int i = 0; i < 16; ++i) {
        int c = i * 4 + ty;
        WT[(size_t)(c0 + c) * rows + r0 + tx] = f2b(tile[tx][c]);
    }
}

// ---- kernel 3: QKV GEMM, 256x256 tile, BK=64, 8-wave 8-phase ---------
// C[4096,3072] = A[4096,1024] * BT[3072,1024]^T, all bf16.
// LDS (128 KiB dynamic): slot(kt&1)*32768 + [A: half*8192 | B: 16384 +
//   half*8192] + chunk(wid)*1024 + khalf*512 + r*32 + g*8 + j, holding
//   T[row = half*128 + wid*16 + r][k = kt*64 + khalf*32 + g*8 + j].
//   Every ds_read_b128 covers 1024 contiguous bytes (0 bank conflicts);
//   global_load_lds stages with a linear LDS dest + permuted global src.
// Region liveness in the CURRENT slot (corrected from round 4):
//   A-half(wr): chunks 0-3 read in q0, chunks 4-7 read in q2  -> A dead
//     only after q2's closing barrier.
//   B-half(wc>>1): read in q0 (ni0-1) and q1 (ni2-3) -> B dead after
//     q1's closing barrier.
// Therefore: stage tile kt+2 ONLY, same-slot, B-halves in q2, A-halves
// in q3. No staging at q0/q1 (round 4's q1 STG into live A was the race).
// vmcnt: at q3-end in-flight = 8 (tile kt+1, staged kt-1) + 8 (tile
// kt+2, staged kt) = 16 -> vmcnt(8) drains exactly tile kt+1 before its
// q0 reads. kt==14: vmcnt(0) drains tile 15. Prologue: tiles 0,1 + drain.
__global__ __launch_bounds__(512, 2) void k_gemm_qkv8(const u16* __restrict__ A,
                                                      const u16* __restrict__ BT,
                                                      u16* __restrict__ C) {
    extern __shared__ __align__(16) u16 lds[];
    const int tid = threadIdx.x, wid = tid >> 6, lane = tid & 63;
    const int r = lane & 15, g = lane >> 4;
    const int wr = wid >> 2, wc = wid & 3;
    const int m0 = blockIdx.y * 256, n0 = blockIdx.x * 256;
    const int K = DMODEL;

    auto STG = [&](int kt2, int rg) {
        const int isB = rg >> 1, half = rg & 1;
        const u16* src = isB ? BT : A;
        const int rowb = (isB ? n0 : m0) + half * 128 + wid * 16 + (lane >> 2);
        const u16* s = src + (size_t)rowb * K + kt2 * 64 + (lane & 3) * 8;
        const int dst = (kt2 & 1) * 32768 + isB * 16384 + half * 8192 +
                        wid * 1024 + lane * 8;
        gl_lds16(s, &lds[dst]);
        gl_lds16(s + 32, &lds[dst + 512]);
    };

    f32x4 acc[8][4] = {};
    bf16x8 a[4][2], b[4][2];
    const int aB = wr * 8192 + r * 32 + g * 8;
    const int bB = 16384 + (wc >> 1) * 8192 + (wc & 1) * 4096 + r * 32 + g * 8;

    // prologue: fully stage tiles 0 and 1
#pragma unroll
    for (int t2 = 0; t2 < 2; ++t2)
#pragma unroll
        for (int rg = 0; rg < 4; ++rg) STG(t2, rg);
    asm volatile("s_waitcnt vmcnt(0)" ::: "memory");
    __syncthreads();

    for (int kt = 0; kt < 16; ++kt) {
        const int sb = (kt & 1) * 32768;
        // ---------------- phase q0: MFMA mi0-3 x ni0-1 ----------------
#pragma unroll
        for (int mi = 0; mi < 4; ++mi)
#pragma unroll
            for (int kk = 0; kk < 2; ++kk)
                a[mi][kk] = *(const bf16x8*)&lds[sb + aB + (mi * 2 + kk) * 512];
#pragma unroll
        for (int ni = 0; ni < 2; ++ni)
#pragma unroll
            for (int kk = 0; kk < 2; ++kk)
                b[ni][kk] = *(const bf16x8*)&lds[sb + bB + (ni * 2 + kk) * 512];
        BAR();
        __builtin_amdgcn_s_setprio(1);
#pragma unroll
        for (int mi = 0; mi < 4; ++mi)
#pragma unroll
            for (int ni = 0; ni < 2; ++ni)
#pragma unroll
                for (int kk = 0; kk < 2; ++kk)
                    acc[mi][ni] = __builtin_amdgcn_mfma_f32_16x16x32_bf16(
                        b[ni][kk], a[mi][kk], acc[mi][ni], 0, 0, 0);
        __builtin_amdgcn_s_setprio(0);
        BAR();
        // ---------------- phase q1: MFMA mi0-3 x ni2-3 ----------------
#pragma unroll
        for (int ni = 2; ni < 4; ++ni)
#pragma unroll
            for (int kk = 0; kk < 2; ++kk)
                b[ni][kk] = *(const bf16x8*)&lds[sb + bB + (ni * 2 + kk) * 512];
        BAR();
        __builtin_amdgcn_s_setprio(1);
#pragma unroll
        for (int mi = 0; mi < 4; ++mi)
#pragma unroll
            for (int ni = 2; ni < 4; ++ni)
#pragma unroll
                for (int kk = 0; kk < 2; ++kk)
                    acc[mi][ni] = __builtin_amdgcn_mfma_f32_16x16x32_bf16(
                        b[ni][kk], a[mi][kk], acc[mi][ni], 0, 0, 0);
        __builtin_amdgcn_s_setprio(0);
        BAR();
        // ---------------- phase q2: MFMA mi4-7 x ni2-3 ----------------
        // stage B-halves of tile kt+2 (B region dead since q1-close)
#pragma unroll
        for (int mi = 0; mi < 4; ++mi)
#pragma unroll
            for (int kk = 0; kk < 2; ++kk)
                a[mi][kk] = *(const bf16x8*)&lds[sb + aB + ((4 + mi) * 2 + kk) * 512];
        if (kt < 14) { STG(kt + 2, 2); STG(kt + 2, 3); }
        BAR();
        __builtin_amdgcn_s_setprio(1);
#pragma unroll
        for (int mi = 0; mi < 4; ++mi)
#pragma unroll
            for (int ni = 2; ni < 4; ++ni)
#pragma unroll
                for (int kk = 0; kk < 2; ++kk)
                    acc[4 + mi][ni] = __builtin_amdgcn_mfma_f32_16x16x32_bf16(
                        b[ni][kk], a[mi][kk], acc[4 + mi][ni], 0, 0, 0);
        __builtin_amdgcn_s_setprio(0);
        BAR();
        // ---------------- phase q3: MFMA mi4-7 x ni0-1 ----------------
        // stage A-halves of tile kt+2 (A region dead since q2-close)
        if (kt < 14) { STG(kt + 2, 0); STG(kt + 2, 1); }
        BAR();
        __builtin_amdgcn_s_setprio(1);
#pragma unroll
        for (int mi = 0; mi < 4; ++mi)
#pragma unroll
            for (int ni = 0; ni < 2; ++ni)
#pragma unroll
                for (int kk = 0; kk < 2; ++kk)
                    acc[4 + mi][ni] = __builtin_amdgcn_mfma_f32_16x16x32_bf16(
                        b[ni][kk], a[mi][kk], acc[4 + mi][ni], 0, 0, 0);
        __builtin_amdgcn_s_setprio(0);
        if (kt < 14) {
            asm volatile("s_waitcnt vmcnt(8)" ::: "memory");
        } else if (kt == 14) {
            asm volatile("s_waitcnt vmcnt(0)" ::: "memory");
        }
        BAR();
    }

    // epilogue: bf16 store, 8B per fragment
#pragma unroll
    for (int mi = 0; mi < 8; ++mi)
#pragma unroll
        for (int ni = 0; ni < 4; ++ni) {
            const int row = m0 + wr * 128 + mi * 16 + r;
            const int col = n0 + wc * 64 + ni * 16 + g * 4;
            union { uint32_t w[2]; ushort4 v; } o;
            o.w[0] = cvt_pk(acc[mi][ni][0], acc[mi][ni][1]);
            o.w[1] = cvt_pk(acc[mi][ni][2], acc[mi][ni][3]);
            *(ushort4*)&C[(size_t)row * QKV_N + col] = o.v;
        }
}

// ---- kernel 3b (proj): C[M,N] = A[M,K] * BT[N,K]^T  (128^2, f32 out) --
template <bool F32OUT>
__global__ __launch_bounds__(256) void k_gemm_bt(const u16* __restrict__ A,
                                                 const u16* __restrict__ BT,
                                                 void* __restrict__ C,
                                                 int M, int N, int K) {
    __shared__ __align__(16) u16 As[128 * 64];
    __shared__ __align__(16) u16 Bs[128 * 64];
    const int tid = threadIdx.x;
    const int wid = tid >> 6, lane = tid & 63;
    const int r = lane & 15, g = lane >> 4;
    const int m0 = blockIdx.y * 128, n0 = blockIdx.x * 128;
    const int wm = (wid >> 1) * 64, wn = (wid & 1) * 64;
    const int srow = lane >> 3, scol = (lane & 7) * 8;
    f32x4 acc[4][4] = {};
    for (int k0 = 0; k0 < K; k0 += 64) {
#pragma unroll
        for (int i = 0; i < 4; ++i) {
            const int li = wid * 4 + i;
            gl_lds16(A + (size_t)(m0 + li * 8 + srow) * K + k0 + scol, &As[li * 512]);
            gl_lds16(BT + (size_t)(n0 + li * 8 + srow) * K + k0 + scol, &Bs[li * 512]);
        }
        __syncthreads();
#pragma unroll
        for (int kk = 0; kk < 2; ++kk) {
            bf16x8 af[4], bfr[4];
#pragma unroll
            for (int mi = 0; mi < 4; ++mi)
                af[mi] = *(const bf16x8*)&As[(wm + mi * 16 + r) * 64 + kk * 32 + g * 8];
#pragma unroll
            for (int ni = 0; ni < 4; ++ni)
                bfr[ni] = *(const bf16x8*)&Bs[(wn + ni * 16 + r) * 64 + kk * 32 + g * 8];
#pragma unroll
            for (int mi = 0; mi < 4; ++mi)
#pragma unroll
                for (int ni = 0; ni < 4; ++ni)
                    acc[mi][ni] = __builtin_amdgcn_mfma_f32_16x16x32_bf16(
                        bfr[ni], af[mi], acc[mi][ni], 0, 0, 0);
        }
        __syncthreads();
    }
#pragma unroll
    for (int mi = 0; mi < 4; ++mi)
#pragma unroll
        for (int ni = 0; ni < 4; ++ni) {
            const int row = m0 + wm + mi * 16 + r;
            const int col = n0 + wn + ni * 16 + g * 4;
            if (F32OUT) {
                float4 vv;
                vv.x = acc[mi][ni][0]; vv.y = acc[mi][ni][1];
                vv.z = acc[mi][ni][2]; vv.w = acc[mi][ni][3];
                *(float4*)&((float*)C)[(size_t)row * N + col] = vv;
            } else {
                union { uint32_t w[2]; ushort4 v; } o;
                o.w[0] = cvt_pk(acc[mi][ni][0], acc[mi][ni][1]);
                o.w[1] = cvt_pk(acc[mi][ni][2], acc[mi][ni][3]);
                *(ushort4*)&((u16*)C)[(size_t)row * N + col] = o.v;
            }
        }
}

// ---- kernel 4: Vt[b][h][hd][s] <- qkv V slice ------------------------
__global__ __launch_bounds__(256) void k_vtrans(const u16* __restrict__ qkv,
                                                u16* __restrict__ Vt) {
    __shared__ u16 tile[64][65];
    const int bh = blockIdx.y;
    const int b = bh >> 4, h = bh & 15;
    const int s0 = blockIdx.x * 64;
    const int tx = threadIdx.x & 63, ty = threadIdx.x >> 6;
#pragma unroll
    for (int i = 0; i < 16; ++i) {
        int s = i * 4 + ty;
        tile[s][tx] = qkv[(size_t)(b * SEQ + s0 + s) * QKV_N + 2 * DMODEL + h * HDIM + tx];
    }
    __syncthreads();
#pragma unroll
    for (int i = 0; i < 16; ++i) {
        int hd = i * 4 + ty;
        Vt[((size_t)bh * HDIM + hd) * SEQ + s0 + tx] = tile[tx][hd];
    }
}

// ---- kernel 5: flash attention v4 ------------------------------------
// Swapped QK^T, in-register softmax, zero-exchange PV, 2-phase dbuf,
// lane-local defer-max (no cross-lane ops in the fast path).
__global__ __launch_bounds__(256) void k_attn(const u16* __restrict__ qkv,
                                              const u16* __restrict__ Vt,
                                              u16* __restrict__ O) {
    __shared__ __align__(16) u16 Ks[2][4096];
    __shared__ __align__(16) u16 Vs[2][4096];
    const int bh = blockIdx.y;
    const int b = bh >> 4, h = bh & 15;
    const int q0 = blockIdx.x * 64;
    const int tid = threadIdx.x, wid = tid >> 6, lane = tid & 63;
    const int r = lane & 15, g = lane >> 4;

    const size_t qbase = (size_t)(b * SEQ + q0 + wid * 16 + r) * QKV_N + h * HDIM;
    const bf16x8 qf0 = *(const bf16x8*)&qkv[qbase + g * 8];
    const bf16x8 qf1 = *(const bf16x8*)&qkv[qbase + 32 + g * 8];

    float mL = -1e30f, lsum = 0.f;
    f32x4 oacc[4] = {};
    const int kc0 = wid * 2;

#define STAGE(BUF, SK0)                                                          \
    {                                                                            \
        _Pragma("unroll") for (int i = 0; i < 2; ++i) {                          \
            const int kc = kc0 + i;                                              \
            const int ksrow = (kc >> 2) * 32 + g * 8 + (kc & 1) * 4 + ((lane >> 2) & 3); \
            const int kscol = ((kc >> 1) & 1) * 32 + (lane & 3) * 8;             \
            gl_lds16(&qkv[(size_t)(b * SEQ + (SK0) + ksrow) * QKV_N + DMODEL +   \
                          h * HDIM + kscol],                                     \
                     &Ks[BUF][kc * 512]);                                        \
            const int vhd = (kc & 3) * 16 + r;                                   \
            const int vsc = (kc >> 2) * 32 + g * 8;                              \
            gl_lds16(&Vt[((size_t)bh * HDIM + vhd) * SEQ + (SK0) + vsc],         \
                     &Vs[BUF][kc * 512]);                                        \
        }                                                                        \
    }

    STAGE(0, 0);
    asm volatile("s_waitcnt vmcnt(0)");
    __syncthreads();

    for (int t = 0; t < SEQ / 64; ++t) {
        const int cur = t & 1;
        if (t < SEQ / 64 - 1) STAGE(cur ^ 1, (t + 1) * 64);

        f32x4 sacc[4] = {};
        __builtin_amdgcn_s_setprio(1);
#pragma unroll
        for (int nf = 0; nf < 4; ++nf) {
            const int kbase = (nf & 1) * 2048 + (nf >> 1) * 512 +
                              (r >> 2) * 128 + (r & 3) * 32 + g * 8;
            bf16x8 kf0 = *(const bf16x8*)&Ks[cur][kbase];
            bf16x8 kf1 = *(const bf16x8*)&Ks[cur][kbase + 1024];
            sacc[nf] = __builtin_amdgcn_mfma_f32_16x16x32_bf16(kf0, qf0, sacc[nf], 0, 0, 0);
            sacc[nf] = __builtin_amdgcn_mfma_f32_16x16x32_bf16(kf1, qf1, sacc[nf], 0, 0, 0);
        }
        __builtin_amdgcn_s_setprio(0);

        // lane-local max (triples to encourage v_max3)
        float m0a = fmaxf(fmaxf(sacc[0][0], sacc[0][1]), fmaxf(sacc[0][2], sacc[0][3]));
        float m1a = fmaxf(fmaxf(sacc[1][0], sacc[1][1]), fmaxf(sacc[1][2], sacc[1][3]));
        float m2a = fmaxf(fmaxf(sacc[2][0], sacc[2][1]), fmaxf(sacc[2][2], sacc[2][3]));
        float m3a = fmaxf(fmaxf(sacc[3][0], sacc[3][1]), fmaxf(sacc[3][2], sacc[3][3]));
        const float pm = fmaxf(fmaxf(m0a, m1a), fmaxf(m2a, m3a)) * C2;
        if (!__all(pm <= mL + 8.f)) {     // slow path: real max growth
            float rm = pm;
            rm = fmaxf(rm, __shfl_xor(rm, 16, 64));
            rm = fmaxf(rm, __shfl_xor(rm, 32, 64));
            const float mNew = fmaxf(mL, rm);
            const float al = exp2f(mL - mNew);
            mL = mNew;
            lsum *= al;
#pragma unroll
            for (int ht = 0; ht < 4; ++ht)
#pragma unroll
                for (int e = 0; e < 4; ++e) oacc[ht][e] *= al;
        }
        float p[4][4];
#pragma unroll
        for (int nf = 0; nf < 4; ++nf)
#pragma unroll
            for (int e = 0; e < 4; ++e) {
                p[nf][e] = exp2f(sacc[nf][e] * C2 - mL);
                lsum += p[nf][e];
            }

        union { uint32_t w[4]; bf16x8 v; } upf0, upf1;
        upf0.w[0] = cvt_pk(p[0][0], p[0][1]);
        upf0.w[1] = cvt_pk(p[0][2], p[0][3]);
        upf0.w[2] = cvt_pk(p[2][0], p[2][1]);
        upf0.w[3] = cvt_pk(p[2][2], p[2][3]);
        upf1.w[0] = cvt_pk(p[1][0], p[1][1]);
        upf1.w[1] = cvt_pk(p[1][2], p[1][3]);
        upf1.w[2] = cvt_pk(p[3][0], p[3][1]);
        upf1.w[3] = cvt_pk(p[3][2], p[3][3]);

        __builtin_amdgcn_s_setprio(1);
#pragma unroll
        for (int ht = 0; ht < 4; ++ht) {
            bf16x8 vf0 = *(const bf16x8*)&Vs[cur][ht * 512 + g * 128 + r * 8];
            bf16x8 vf1 = *(const bf16x8*)&Vs[cur][(4 + ht) * 512 + g * 128 + r * 8];
            oacc[ht] = __builtin_amdgcn_mfma_f32_16x16x32_bf16(vf0, upf0.v, oacc[ht], 0, 0, 0);
            oacc[ht] = __builtin_amdgcn_mfma_f32_16x16x32_bf16(vf1, upf1.v, oacc[ht], 0, 0, 0);
        }
        __builtin_amdgcn_s_setprio(0);

        asm volatile("s_waitcnt vmcnt(0)");
        __syncthreads();
    }
#undef STAGE

    lsum += __shfl_xor(lsum, 16, 64);
    lsum += __shfl_xor(lsum, 32, 64);
    const float inv = 1.0f / lsum;
    const size_t obase = (size_t)(b * SEQ + q0 + wid * 16 + r) * DMODEL + h * HDIM;
#pragma unroll
    for (int ht = 0; ht < 4; ++ht) {
        union { uint32_t w[2]; ushort4 v; } o;
        o.w[0] = cvt_pk(oacc[ht][0] * inv, oacc[ht][1] * inv);
        o.w[1] = cvt_pk(oacc[ht][2] * inv, oacc[ht][3] * inv);
        *(ushort4*)&O[obase + ht * 16 + g * 4] = o.v;
    }
}

// ---- launcher --------------------------------------------------------
extern "C" void kernel_launch(void* const* d_in, const int* in_sizes, int n_in,
                              void* d_out, int out_size, void* d_ws, size_t ws_size,
                              hipStream_t stream) {
    const float* x = (const float*)d_in[0];
    const float* Wqkv = (const float*)d_in[1];
    const float* Wproj = (const float*)d_in[2];
    float* out = (float*)d_out;

    u16* xb = (u16*)d_ws;                                  //  8 MB
    u16* WqkvT = xb + (size_t)MTOT * DMODEL;               //  6 MB
    u16* WprojT = WqkvT + (size_t)QKV_N * DMODEL;          //  2 MB
    u16* qkv = WprojT + (size_t)DMODEL * DMODEL;           // 24 MB
    u16* Vt = qkv + (size_t)MTOT * QKV_N;                  //  8 MB
    u16* Ob = Vt + (size_t)BATCH * NH * HDIM * SEQ;        //  8 MB

    hipFuncSetAttribute(reinterpret_cast<const void*>(k_gemm_qkv8),
                        hipFuncAttributeMaxDynamicSharedMemorySize, 131072);

    k_cvt<<<dim3((MTOT * DMODEL / 8) / 256), 256, 0, stream>>>(x, xb, MTOT * DMODEL / 8);
    k_wtrans<<<dim3(QKV_N / 64, DMODEL / 64), 256, 0, stream>>>(Wqkv, WqkvT, DMODEL, QKV_N);
    k_wtrans<<<dim3(DMODEL / 64, DMODEL / 64), 256, 0, stream>>>(Wproj, WprojT, DMODEL, DMODEL);
    k_gemm_qkv8<<<dim3(QKV_N / 256, MTOT / 256), 512, 131072, stream>>>(xb, WqkvT, qkv);
    k_vtrans<<<dim3(SEQ / 64, BATCH * NH), 256, 0, stream>>>(qkv, Vt);
    k_attn<<<dim3(SEQ / 64, BATCH * NH), 256, 0, stream>>>(qkv, Vt, Ob);
    k_gemm_bt<true><<<dim3(DMODEL / 128, MTOT / 128), 256, 0, stream>>>(
        Ob, WprojT, (void*)out, MTOT, DMODEL, DMODEL);
}

// Round 6
// 216.755 us; speedup vs baseline: 1.4463x; 1.0625x over previous
//
#include <hip/hip_runtime.h>
#include <stdint.h>

typedef unsigned short u16;
typedef __attribute__((ext_vector_type(8))) short bf16x8;
typedef __attribute__((ext_vector_type(4))) float f32x4;

#define BATCH 2
#define SEQ 2048
#define NH 16
#define HDIM 64
#define DMODEL 1024
#define MTOT (BATCH * SEQ)      // 4096
#define QKV_N (3 * DMODEL)      // 3072
#define ATT_SCALE 0.125f
#define L2E 1.44269504088896340736f
#define C2 (ATT_SCALE * L2E)

#define BAR() asm volatile("s_barrier" ::: "memory")
#define F3(a, b, c) fmaxf(fmaxf((a), (b)), (c))   // fuses to v_max3_f32

// ---- helpers ----------------------------------------------------------
__device__ __forceinline__ u16 f2b(float f) {
    uint32_t x = __builtin_bit_cast(uint32_t, f);
    uint32_t r = (x + 0x7fffu + ((x >> 16) & 1u)) >> 16;
    return (u16)r;
}

__device__ __forceinline__ uint32_t cvt_pk(float lo, float hi) {
    uint32_t r;
    asm("v_cvt_pk_bf16_f32 %0, %1, %2" : "=v"(r) : "v"(lo), "v"(hi));
    return r;
}

__device__ __forceinline__ void gl_lds16(const void* g, void* l) {
    __builtin_amdgcn_global_load_lds(
        (const __attribute__((address_space(1))) void*)g,
        (__attribute__((address_space(3))) void*)l, 16, 0, 0);
}

// ---- kernel 1: fused prep (cvt x -> bf16; transpose both W -> bf16) ---
// blocks [0,2048): cvt; [2048,2816): Wqkv trans; [2816,3072): Wproj trans
__global__ __launch_bounds__(256) void k_prep(const float* __restrict__ x,
                                              const float* __restrict__ Wq,
                                              const float* __restrict__ Wp,
                                              u16* __restrict__ xb,
                                              u16* __restrict__ WqT,
                                              u16* __restrict__ WpT) {
    const int bid = blockIdx.x, tid = threadIdx.x;
    if (bid < 2048) {
        const int i = bid * 256 + tid;
        const float4* p = (const float4*)x + (size_t)i * 2;
        float4 a = p[0], b = p[1];
        union { uint32_t w[4]; uint4 v; } u;
        u.w[0] = cvt_pk(a.x, a.y);
        u.w[1] = cvt_pk(a.z, a.w);
        u.w[2] = cvt_pk(b.x, b.y);
        u.w[3] = cvt_pk(b.z, b.w);
        *(uint4*)(xb + (size_t)i * 8) = u.v;
        return;
    }
    __shared__ float tile[64][65];
    const float* W;
    u16* WT;
    int cols, bx, by;
    if (bid < 2048 + 768) {
        const int j = bid - 2048;
        W = Wq; WT = WqT; cols = QKV_N; bx = j % 48; by = j / 48;
    } else {
        const int j = bid - 2816;
        W = Wp; WT = WpT; cols = DMODEL; bx = j % 16; by = j / 16;
    }
    const int rows = DMODEL;
    const int c0 = bx * 64, r0 = by * 64;
    const int tx = tid & 63, ty = tid >> 6;
#pragma unroll
    for (int i = 0; i < 16; ++i) {
        int r = i * 4 + ty;
        tile[r][tx] = W[(size_t)(r0 + r) * cols + c0 + tx];
    }
    __syncthreads();
#pragma unroll
    for (int i = 0; i < 16; ++i) {
        int c = i * 4 + ty;
        WT[(size_t)(c0 + c) * rows + r0 + tx] = f2b(tile[tx][c]);
    }
}

// ---- kernel 2: QKV GEMM, 256x256 tile, BK=64, 8-wave 8-phase ---------
// Same verified schedule as round 5. New: V-region blocks (n0 >= 2048)
// write straight into Vt[b*16+h][hd][s] (4 x 2B stores per fragment,
// 32B/16-lane-group segments) and skip the qkv-layout V store, removing
// the k_vtrans pass entirely.
__global__ __launch_bounds__(512, 2) void k_gemm_qkv8(const u16* __restrict__ A,
                                                      const u16* __restrict__ BT,
                                                      u16* __restrict__ C,
                                                      u16* __restrict__ Vt) {
    extern __shared__ __align__(16) u16 lds[];
    const int tid = threadIdx.x, wid = tid >> 6, lane = tid & 63;
    const int r = lane & 15, g = lane >> 4;
    const int wr = wid >> 2, wc = wid & 3;
    const int m0 = blockIdx.y * 256, n0 = blockIdx.x * 256;
    const int K = DMODEL;

    auto STG = [&](int kt2, int rg) {
        const int isB = rg >> 1, half = rg & 1;
        const u16* src = isB ? BT : A;
        const int rowb = (isB ? n0 : m0) + half * 128 + wid * 16 + (lane >> 2);
        const u16* s = src + (size_t)rowb * K + kt2 * 64 + (lane & 3) * 8;
        const int dst = (kt2 & 1) * 32768 + isB * 16384 + half * 8192 +
                        wid * 1024 + lane * 8;
        gl_lds16(s, &lds[dst]);
        gl_lds16(s + 32, &lds[dst + 512]);
    };

    f32x4 acc[8][4] = {};
    bf16x8 a[4][2], b[4][2];
    const int aB = wr * 8192 + r * 32 + g * 8;
    const int bB = 16384 + (wc >> 1) * 8192 + (wc & 1) * 4096 + r * 32 + g * 8;

#pragma unroll
    for (int t2 = 0; t2 < 2; ++t2)
#pragma unroll
        for (int rg = 0; rg < 4; ++rg) STG(t2, rg);
    asm volatile("s_waitcnt vmcnt(0)" ::: "memory");
    __syncthreads();

    for (int kt = 0; kt < 16; ++kt) {
        const int sb = (kt & 1) * 32768;
        // q0: MFMA mi0-3 x ni0-1
#pragma unroll
        for (int mi = 0; mi < 4; ++mi)
#pragma unroll
            for (int kk = 0; kk < 2; ++kk)
                a[mi][kk] = *(const bf16x8*)&lds[sb + aB + (mi * 2 + kk) * 512];
#pragma unroll
        for (int ni = 0; ni < 2; ++ni)
#pragma unroll
            for (int kk = 0; kk < 2; ++kk)
                b[ni][kk] = *(const bf16x8*)&lds[sb + bB + (ni * 2 + kk) * 512];
        BAR();
        __builtin_amdgcn_s_setprio(1);
#pragma unroll
        for (int mi = 0; mi < 4; ++mi)
#pragma unroll
            for (int ni = 0; ni < 2; ++ni)
#pragma unroll
                for (int kk = 0; kk < 2; ++kk)
                    acc[mi][ni] = __builtin_amdgcn_mfma_f32_16x16x32_bf16(
                        b[ni][kk], a[mi][kk], acc[mi][ni], 0, 0, 0);
        __builtin_amdgcn_s_setprio(0);
        BAR();
        // q1: MFMA mi0-3 x ni2-3
#pragma unroll
        for (int ni = 2; ni < 4; ++ni)
#pragma unroll
            for (int kk = 0; kk < 2; ++kk)
                b[ni][kk] = *(const bf16x8*)&lds[sb + bB + (ni * 2 + kk) * 512];
        BAR();
        __builtin_amdgcn_s_setprio(1);
#pragma unroll
        for (int mi = 0; mi < 4; ++mi)
#pragma unroll
            for (int ni = 2; ni < 4; ++ni)
#pragma unroll
                for (int kk = 0; kk < 2; ++kk)
                    acc[mi][ni] = __builtin_amdgcn_mfma_f32_16x16x32_bf16(
                        b[ni][kk], a[mi][kk], acc[mi][ni], 0, 0, 0);
        __builtin_amdgcn_s_setprio(0);
        BAR();
        // q2: MFMA mi4-7 x ni2-3 ; stage B(kt+2) (B dead since q1-close)
#pragma unroll
        for (int mi = 0; mi < 4; ++mi)
#pragma unroll
            for (int kk = 0; kk < 2; ++kk)
                a[mi][kk] = *(const bf16x8*)&lds[sb + aB + ((4 + mi) * 2 + kk) * 512];
        if (kt < 14) { STG(kt + 2, 2); STG(kt + 2, 3); }
        BAR();
        __builtin_amdgcn_s_setprio(1);
#pragma unroll
        for (int mi = 0; mi < 4; ++mi)
#pragma unroll
            for (int ni = 2; ni < 4; ++ni)
#pragma unroll
                for (int kk = 0; kk < 2; ++kk)
                    acc[4 + mi][ni] = __builtin_amdgcn_mfma_f32_16x16x32_bf16(
                        b[ni][kk], a[mi][kk], acc[4 + mi][ni], 0, 0, 0);
        __builtin_amdgcn_s_setprio(0);
        BAR();
        // q3: MFMA mi4-7 x ni0-1 ; stage A(kt+2) (A dead since q2-close)
        if (kt < 14) { STG(kt + 2, 0); STG(kt + 2, 1); }
        BAR();
        __builtin_amdgcn_s_setprio(1);
#pragma unroll
        for (int mi = 0; mi < 4; ++mi)
#pragma unroll
            for (int ni = 0; ni < 2; ++ni)
#pragma unroll
                for (int kk = 0; kk < 2; ++kk)
                    acc[4 + mi][ni] = __builtin_amdgcn_mfma_f32_16x16x32_bf16(
                        b[ni][kk], a[mi][kk], acc[4 + mi][ni], 0, 0, 0);
        __builtin_amdgcn_s_setprio(0);
        if (kt < 14) {
            asm volatile("s_waitcnt vmcnt(8)" ::: "memory");
        } else if (kt == 14) {
            asm volatile("s_waitcnt vmcnt(0)" ::: "memory");
        }
        BAR();
    }

    if (n0 < 2 * DMODEL) {
        // Q/K region: normal row-major bf16 store
#pragma unroll
        for (int mi = 0; mi < 8; ++mi)
#pragma unroll
            for (int ni = 0; ni < 4; ++ni) {
                const int row = m0 + wr * 128 + mi * 16 + r;
                const int col = n0 + wc * 64 + ni * 16 + g * 4;
                union { uint32_t w[2]; ushort4 v; } o;
                o.w[0] = cvt_pk(acc[mi][ni][0], acc[mi][ni][1]);
                o.w[1] = cvt_pk(acc[mi][ni][2], acc[mi][ni][3]);
                *(ushort4*)&C[(size_t)row * QKV_N + col] = o.v;
            }
    } else {
        // V region: write transposed into Vt[(b*16+h)][hd][s]
        const int h_ = ((n0 - 2 * DMODEL) >> 6) + wc;
#pragma unroll
        for (int mi = 0; mi < 8; ++mi)
#pragma unroll
            for (int ni = 0; ni < 4; ++ni) {
                const int row = m0 + wr * 128 + mi * 16 + r;
                const int b_ = row >> 11, s_ = row & (SEQ - 1);
                const int hd0 = ni * 16 + g * 4;
                union { uint32_t w[2]; u16 t[4]; } o;
                o.w[0] = cvt_pk(acc[mi][ni][0], acc[mi][ni][1]);
                o.w[1] = cvt_pk(acc[mi][ni][2], acc[mi][ni][3]);
                const size_t base =
                    ((size_t)(b_ * NH + h_) * HDIM + hd0) * SEQ + s_;
                Vt[base] = o.t[0];
                Vt[base + SEQ] = o.t[1];
                Vt[base + 2 * SEQ] = o.t[2];
                Vt[base + 3 * SEQ] = o.t[3];
            }
    }
}

// ---- kernel 3: proj GEMM, 64x128 tile (512 blocks -> 2/CU) -----------
__global__ __launch_bounds__(256) void k_gemm_proj(const u16* __restrict__ A,
                                                   const u16* __restrict__ BT,
                                                   float* __restrict__ C) {
    __shared__ __align__(16) u16 As[64 * 64];
    __shared__ __align__(16) u16 Bs[128 * 64];
    const int tid = threadIdx.x;
    const int wid = tid >> 6, lane = tid & 63;
    const int r = lane & 15, g = lane >> 4;
    const int m0 = blockIdx.y * 64, n0 = blockIdx.x * 128;
    const int srow = lane >> 3, scol = (lane & 7) * 8;
    const int K = DMODEL;
    f32x4 acc[4][2] = {};
    for (int k0 = 0; k0 < K; k0 += 64) {
#pragma unroll
        for (int i = 0; i < 2; ++i) {
            const int li = wid * 2 + i;
            gl_lds16(A + (size_t)(m0 + li * 8 + srow) * K + k0 + scol, &As[li * 512]);
        }
#pragma unroll
        for (int i = 0; i < 4; ++i) {
            const int li = wid * 4 + i;
            gl_lds16(BT + (size_t)(n0 + li * 8 + srow) * K + k0 + scol, &Bs[li * 512]);
        }
        __syncthreads();
#pragma unroll
        for (int kk = 0; kk < 2; ++kk) {
            bf16x8 af[4], bfr[2];
#pragma unroll
            for (int mi = 0; mi < 4; ++mi)
                af[mi] = *(const bf16x8*)&As[(mi * 16 + r) * 64 + kk * 32 + g * 8];
#pragma unroll
            for (int ni = 0; ni < 2; ++ni)
                bfr[ni] = *(const bf16x8*)&Bs[(wid * 32 + ni * 16 + r) * 64 + kk * 32 + g * 8];
#pragma unroll
            for (int mi = 0; mi < 4; ++mi)
#pragma unroll
                for (int ni = 0; ni < 2; ++ni)
                    acc[mi][ni] = __builtin_amdgcn_mfma_f32_16x16x32_bf16(
                        bfr[ni], af[mi], acc[mi][ni], 0, 0, 0);
        }
        __syncthreads();
    }
#pragma unroll
    for (int mi = 0; mi < 4; ++mi)
#pragma unroll
        for (int ni = 0; ni < 2; ++ni) {
            const int row = m0 + mi * 16 + r;
            const int col = n0 + wid * 32 + ni * 16 + g * 4;
            float4 vv;
            vv.x = acc[mi][ni][0]; vv.y = acc[mi][ni][1];
            vv.z = acc[mi][ni][2]; vv.w = acc[mi][ni][3];
            *(float4*)&C[(size_t)row * DMODEL + col] = vv;
        }
}

// ---- kernel 4: flash attention v5 ------------------------------------
// Round-5 structure + incremental stage pointers + max3 reduction chain.
__global__ __launch_bounds__(256) void k_attn(const u16* __restrict__ qkv,
                                              const u16* __restrict__ Vt,
                                              u16* __restrict__ O) {
    __shared__ __align__(16) u16 Ks[2][4096];
    __shared__ __align__(16) u16 Vs[2][4096];
    const int bh = blockIdx.y;
    const int b = bh >> 4, h = bh & 15;
    const int q0 = blockIdx.x * 64;
    const int tid = threadIdx.x, wid = tid >> 6, lane = tid & 63;
    const int r = lane & 15, g = lane >> 4;

    const size_t qbase = (size_t)(b * SEQ + q0 + wid * 16 + r) * QKV_N + h * HDIM;
    const bf16x8 qf0 = *(const bf16x8*)&qkv[qbase + g * 8];
    const bf16x8 qf1 = *(const bf16x8*)&qkv[qbase + 32 + g * 8];

    float mL = -1e30f, lsum = 0.f;
    f32x4 oacc[4] = {};
    const int kc0 = wid * 2;

    // incremental staging pointers (advance per tile; no per-tile recompute)
    const u16* kp[2];
    const u16* vp[2];
    int kdst[2], vdst[2];
#pragma unroll
    for (int i = 0; i < 2; ++i) {
        const int kc = kc0 + i;
        const int ksrow = (kc >> 2) * 32 + g * 8 + (kc & 1) * 4 + ((lane >> 2) & 3);
        const int kscol = ((kc >> 1) & 1) * 32 + (lane & 3) * 8;
        kp[i] = qkv + (size_t)(b * SEQ + ksrow) * QKV_N + DMODEL + h * HDIM + kscol;
        const int vhd = (kc & 3) * 16 + r;
        const int vsc = (kc >> 2) * 32 + g * 8;
        vp[i] = Vt + ((size_t)bh * HDIM + vhd) * SEQ + vsc;
        kdst[i] = kc * 512;
        vdst[i] = kc * 512;
    }

#define STAGE(BUF)                                                   \
    {                                                                \
        _Pragma("unroll") for (int i = 0; i < 2; ++i) {              \
            gl_lds16(kp[i], &Ks[BUF][kdst[i]]);                      \
            gl_lds16(vp[i], &Vs[BUF][vdst[i]]);                      \
            kp[i] += 64 * QKV_N;                                     \
            vp[i] += 64;                                             \
        }                                                            \
    }

    STAGE(0);
    asm volatile("s_waitcnt vmcnt(0)");
    __syncthreads();

    for (int t = 0; t < SEQ / 64; ++t) {
        const int cur = t & 1;
        if (t < SEQ / 64 - 1) STAGE(cur ^ 1);

        f32x4 sacc[4] = {};
        __builtin_amdgcn_s_setprio(1);
#pragma unroll
        for (int nf = 0; nf < 4; ++nf) {
            const int kbase = (nf & 1) * 2048 + (nf >> 1) * 512 +
                              (r >> 2) * 128 + (r & 3) * 32 + g * 8;
            bf16x8 kf0 = *(const bf16x8*)&Ks[cur][kbase];
            bf16x8 kf1 = *(const bf16x8*)&Ks[cur][kbase + 1024];
            sacc[nf] = __builtin_amdgcn_mfma_f32_16x16x32_bf16(kf0, qf0, sacc[nf], 0, 0, 0);
            sacc[nf] = __builtin_amdgcn_mfma_f32_16x16x32_bf16(kf1, qf1, sacc[nf], 0, 0, 0);
        }
        __builtin_amdgcn_s_setprio(0);

        // lane-local max via v_max3 chain (8 ops for 16 values)
        float mt = F3(sacc[0][0], sacc[0][1], sacc[0][2]);
        mt = F3(mt, sacc[0][3], sacc[1][0]);
        mt = F3(mt, sacc[1][1], sacc[1][2]);
        mt = F3(mt, sacc[1][3], sacc[2][0]);
        mt = F3(mt, sacc[2][1], sacc[2][2]);
        mt = F3(mt, sacc[2][3], sacc[3][0]);
        mt = F3(mt, sacc[3][1], sacc[3][2]);
        mt = fmaxf(mt, sacc[3][3]);
        const float pm = mt * C2;
        if (!__all(pm <= mL + 8.f)) {
            float rm = pm;
            rm = fmaxf(rm, __shfl_xor(rm, 16, 64));
            rm = fmaxf(rm, __shfl_xor(rm, 32, 64));
            const float mNew = fmaxf(mL, rm);
            const float al = exp2f(mL - mNew);
            mL = mNew;
            lsum *= al;
#pragma unroll
            for (int ht = 0; ht < 4; ++ht)
#pragma unroll
                for (int e = 0; e < 4; ++e) oacc[ht][e] *= al;
        }
        float p[4][4];
#pragma unroll
        for (int nf = 0; nf < 4; ++nf)
#pragma unroll
            for (int e = 0; e < 4; ++e) {
                p[nf][e] = exp2f(sacc[nf][e] * C2 - mL);
                lsum += p[nf][e];
            }

        union { uint32_t w[4]; bf16x8 v; } upf0, upf1;
        upf0.w[0] = cvt_pk(p[0][0], p[0][1]);
        upf0.w[1] = cvt_pk(p[0][2], p[0][3]);
        upf0.w[2] = cvt_pk(p[2][0], p[2][1]);
        upf0.w[3] = cvt_pk(p[2][2], p[2][3]);
        upf1.w[0] = cvt_pk(p[1][0], p[1][1]);
        upf1.w[1] = cvt_pk(p[1][2], p[1][3]);
        upf1.w[2] = cvt_pk(p[3][0], p[3][1]);
        upf1.w[3] = cvt_pk(p[3][2], p[3][3]);

        __builtin_amdgcn_s_setprio(1);
#pragma unroll
        for (int ht = 0; ht < 4; ++ht) {
            bf16x8 vf0 = *(const bf16x8*)&Vs[cur][ht * 512 + g * 128 + r * 8];
            bf16x8 vf1 = *(const bf16x8*)&Vs[cur][(4 + ht) * 512 + g * 128 + r * 8];
            oacc[ht] = __builtin_amdgcn_mfma_f32_16x16x32_bf16(vf0, upf0.v, oacc[ht], 0, 0, 0);
            oacc[ht] = __builtin_amdgcn_mfma_f32_16x16x32_bf16(vf1, upf1.v, oacc[ht], 0, 0, 0);
        }
        __builtin_amdgcn_s_setprio(0);

        asm volatile("s_waitcnt vmcnt(0)");
        __syncthreads();
    }
#undef STAGE

    lsum += __shfl_xor(lsum, 16, 64);
    lsum += __shfl_xor(lsum, 32, 64);
    const float inv = 1.0f / lsum;
    const size_t obase = (size_t)(b * SEQ + q0 + wid * 16 + r) * DMODEL + h * HDIM;
#pragma unroll
    for (int ht = 0; ht < 4; ++ht) {
        union { uint32_t w[2]; ushort4 v; } o;
        o.w[0] = cvt_pk(oacc[ht][0] * inv, oacc[ht][1] * inv);
        o.w[1] = cvt_pk(oacc[ht][2] * inv, oacc[ht][3] * inv);
        *(ushort4*)&O[obase + ht * 16 + g * 4] = o.v;
    }
}

// ---- launcher --------------------------------------------------------
extern "C" void kernel_launch(void* const* d_in, const int* in_sizes, int n_in,
                              void* d_out, int out_size, void* d_ws, size_t ws_size,
                              hipStream_t stream) {
    const float* x = (const float*)d_in[0];
    const float* Wqkv = (const float*)d_in[1];
    const float* Wproj = (const float*)d_in[2];
    float* out = (float*)d_out;

    u16* xb = (u16*)d_ws;                                  //  8 MB
    u16* WqkvT = xb + (size_t)MTOT * DMODEL;               //  6 MB
    u16* WprojT = WqkvT + (size_t)QKV_N * DMODEL;          //  2 MB
    u16* qkv = WprojT + (size_t)DMODEL * DMODEL;           // 24 MB (V third unused)
    u16* Vt = qkv + (size_t)MTOT * QKV_N;                  //  8 MB
    u16* Ob = Vt + (size_t)BATCH * NH * HDIM * SEQ;        //  8 MB

    hipFuncSetAttribute(reinterpret_cast<const void*>(k_gemm_qkv8),
                        hipFuncAttributeMaxDynamicSharedMemorySize, 131072);

    k_prep<<<dim3(3072), 256, 0, stream>>>(x, Wqkv, Wproj, xb, WqkvT, WprojT);
    k_gemm_qkv8<<<dim3(QKV_N / 256, MTOT / 256), 512, 131072, stream>>>(
        xb, WqkvT, qkv, Vt);
    k_attn<<<dim3(SEQ / 64, BATCH * NH), 256, 0, stream>>>(qkv, Vt, Ob);
    k_gemm_proj<<<dim3(DMODEL / 128, MTOT / 64), 256, 0, stream>>>(Ob, WprojT, out);
}

// Round 7
// 214.566 us; speedup vs baseline: 1.4610x; 1.0102x over previous
//
#include <hip/hip_runtime.h>
#include <stdint.h>

typedef unsigned short u16;
typedef __attribute__((ext_vector_type(8))) short bf16x8;
typedef __attribute__((ext_vector_type(4))) float f32x4;

#define BATCH 2
#define SEQ 2048
#define NH 16
#define HDIM 64
#define DMODEL 1024
#define MTOT (BATCH * SEQ)      // 4096
#define QKV_N (3 * DMODEL)      // 3072
#define ATT_SCALE 0.125f
#define L2E 1.44269504088896340736f
#define C2 (ATT_SCALE * L2E)

#define BAR() asm volatile("s_barrier" ::: "memory")
#define F3(a, b, c) fmaxf(fmaxf((a), (b)), (c))   // fuses to v_max3_f32

// ---- helpers ----------------------------------------------------------
__device__ __forceinline__ u16 f2b(float f) {
    uint32_t x = __builtin_bit_cast(uint32_t, f);
    uint32_t r = (x + 0x7fffu + ((x >> 16) & 1u)) >> 16;
    return (u16)r;
}

__device__ __forceinline__ uint32_t cvt_pk(float lo, float hi) {
    uint32_t r;
    asm("v_cvt_pk_bf16_f32 %0, %1, %2" : "=v"(r) : "v"(lo), "v"(hi));
    return r;
}

__device__ __forceinline__ void gl_lds16(const void* g, void* l) {
    __builtin_amdgcn_global_load_lds(
        (const __attribute__((address_space(1))) void*)g,
        (__attribute__((address_space(3))) void*)l, 16, 0, 0);
}

// ---- kernel 1: fused prep (cvt x -> bf16; transpose both W -> bf16) ---
__global__ __launch_bounds__(256) void k_prep(const float* __restrict__ x,
                                              const float* __restrict__ Wq,
                                              const float* __restrict__ Wp,
                                              u16* __restrict__ xb,
                                              u16* __restrict__ WqT,
                                              u16* __restrict__ WpT) {
    const int bid = blockIdx.x, tid = threadIdx.x;
    if (bid < 2048) {
        const int i = bid * 256 + tid;
        const float4* p = (const float4*)x + (size_t)i * 2;
        float4 a = p[0], b = p[1];
        union { uint32_t w[4]; uint4 v; } u;
        u.w[0] = cvt_pk(a.x, a.y);
        u.w[1] = cvt_pk(a.z, a.w);
        u.w[2] = cvt_pk(b.x, b.y);
        u.w[3] = cvt_pk(b.z, b.w);
        *(uint4*)(xb + (size_t)i * 8) = u.v;
        return;
    }
    __shared__ float tile[64][65];
    const float* W;
    u16* WT;
    int cols, bx, by;
    if (bid < 2048 + 768) {
        const int j = bid - 2048;
        W = Wq; WT = WqT; cols = QKV_N; bx = j % 48; by = j / 48;
    } else {
        const int j = bid - 2816;
        W = Wp; WT = WpT; cols = DMODEL; bx = j % 16; by = j / 16;
    }
    const int rows = DMODEL;
    const int c0 = bx * 64, r0 = by * 64;
    const int tx = tid & 63, ty = tid >> 6;
#pragma unroll
    for (int i = 0; i < 16; ++i) {
        int r = i * 4 + ty;
        tile[r][tx] = W[(size_t)(r0 + r) * cols + c0 + tx];
    }
    __syncthreads();
#pragma unroll
    for (int i = 0; i < 16; ++i) {
        int c = i * 4 + ty;
        WT[(size_t)(c0 + c) * rows + r0 + tx] = f2b(tile[tx][c]);
    }
}

// ---- kernel 2: QKV GEMM, 256x256 tile, BK=64, 8-wave 8-phase ---------
// (unchanged from round 6 — verified schedule + direct-Vt epilogue)
__global__ __launch_bounds__(512, 2) void k_gemm_qkv8(const u16* __restrict__ A,
                                                      const u16* __restrict__ BT,
                                                      u16* __restrict__ C,
                                                      u16* __restrict__ Vt) {
    extern __shared__ __align__(16) u16 lds[];
    const int tid = threadIdx.x, wid = tid >> 6, lane = tid & 63;
    const int r = lane & 15, g = lane >> 4;
    const int wr = wid >> 2, wc = wid & 3;
    const int m0 = blockIdx.y * 256, n0 = blockIdx.x * 256;
    const int K = DMODEL;

    auto STG = [&](int kt2, int rg) {
        const int isB = rg >> 1, half = rg & 1;
        const u16* src = isB ? BT : A;
        const int rowb = (isB ? n0 : m0) + half * 128 + wid * 16 + (lane >> 2);
        const u16* s = src + (size_t)rowb * K + kt2 * 64 + (lane & 3) * 8;
        const int dst = (kt2 & 1) * 32768 + isB * 16384 + half * 8192 +
                        wid * 1024 + lane * 8;
        gl_lds16(s, &lds[dst]);
        gl_lds16(s + 32, &lds[dst + 512]);
    };

    f32x4 acc[8][4] = {};
    bf16x8 a[4][2], b[4][2];
    const int aB = wr * 8192 + r * 32 + g * 8;
    const int bB = 16384 + (wc >> 1) * 8192 + (wc & 1) * 4096 + r * 32 + g * 8;

#pragma unroll
    for (int t2 = 0; t2 < 2; ++t2)
#pragma unroll
        for (int rg = 0; rg < 4; ++rg) STG(t2, rg);
    asm volatile("s_waitcnt vmcnt(0)" ::: "memory");
    __syncthreads();

    for (int kt = 0; kt < 16; ++kt) {
        const int sb = (kt & 1) * 32768;
        // q0: MFMA mi0-3 x ni0-1
#pragma unroll
        for (int mi = 0; mi < 4; ++mi)
#pragma unroll
            for (int kk = 0; kk < 2; ++kk)
                a[mi][kk] = *(const bf16x8*)&lds[sb + aB + (mi * 2 + kk) * 512];
#pragma unroll
        for (int ni = 0; ni < 2; ++ni)
#pragma unroll
            for (int kk = 0; kk < 2; ++kk)
                b[ni][kk] = *(const bf16x8*)&lds[sb + bB + (ni * 2 + kk) * 512];
        BAR();
        __builtin_amdgcn_s_setprio(1);
#pragma unroll
        for (int mi = 0; mi < 4; ++mi)
#pragma unroll
            for (int ni = 0; ni < 2; ++ni)
#pragma unroll
                for (int kk = 0; kk < 2; ++kk)
                    acc[mi][ni] = __builtin_amdgcn_mfma_f32_16x16x32_bf16(
                        b[ni][kk], a[mi][kk], acc[mi][ni], 0, 0, 0);
        __builtin_amdgcn_s_setprio(0);
        BAR();
        // q1: MFMA mi0-3 x ni2-3
#pragma unroll
        for (int ni = 2; ni < 4; ++ni)
#pragma unroll
            for (int kk = 0; kk < 2; ++kk)
                b[ni][kk] = *(const bf16x8*)&lds[sb + bB + (ni * 2 + kk) * 512];
        BAR();
        __builtin_amdgcn_s_setprio(1);
#pragma unroll
        for (int mi = 0; mi < 4; ++mi)
#pragma unroll
            for (int ni = 2; ni < 4; ++ni)
#pragma unroll
                for (int kk = 0; kk < 2; ++kk)
                    acc[mi][ni] = __builtin_amdgcn_mfma_f32_16x16x32_bf16(
                        b[ni][kk], a[mi][kk], acc[mi][ni], 0, 0, 0);
        __builtin_amdgcn_s_setprio(0);
        BAR();
        // q2: MFMA mi4-7 x ni2-3 ; stage B(kt+2)
#pragma unroll
        for (int mi = 0; mi < 4; ++mi)
#pragma unroll
            for (int kk = 0; kk < 2; ++kk)
                a[mi][kk] = *(const bf16x8*)&lds[sb + aB + ((4 + mi) * 2 + kk) * 512];
        if (kt < 14) { STG(kt + 2, 2); STG(kt + 2, 3); }
        BAR();
        __builtin_amdgcn_s_setprio(1);
#pragma unroll
        for (int mi = 0; mi < 4; ++mi)
#pragma unroll
            for (int ni = 2; ni < 4; ++ni)
#pragma unroll
                for (int kk = 0; kk < 2; ++kk)
                    acc[4 + mi][ni] = __builtin_amdgcn_mfma_f32_16x16x32_bf16(
                        b[ni][kk], a[mi][kk], acc[4 + mi][ni], 0, 0, 0);
        __builtin_amdgcn_s_setprio(0);
        BAR();
        // q3: MFMA mi4-7 x ni0-1 ; stage A(kt+2)
        if (kt < 14) { STG(kt + 2, 0); STG(kt + 2, 1); }
        BAR();
        __builtin_amdgcn_s_setprio(1);
#pragma unroll
        for (int mi = 0; mi < 4; ++mi)
#pragma unroll
            for (int ni = 0; ni < 2; ++ni)
#pragma unroll
                for (int kk = 0; kk < 2; ++kk)
                    acc[4 + mi][ni] = __builtin_amdgcn_mfma_f32_16x16x32_bf16(
                        b[ni][kk], a[mi][kk], acc[4 + mi][ni], 0, 0, 0);
        __builtin_amdgcn_s_setprio(0);
        if (kt < 14) {
            asm volatile("s_waitcnt vmcnt(8)" ::: "memory");
        } else if (kt == 14) {
            asm volatile("s_waitcnt vmcnt(0)" ::: "memory");
        }
        BAR();
    }

    if (n0 < 2 * DMODEL) {
#pragma unroll
        for (int mi = 0; mi < 8; ++mi)
#pragma unroll
            for (int ni = 0; ni < 4; ++ni) {
                const int row = m0 + wr * 128 + mi * 16 + r;
                const int col = n0 + wc * 64 + ni * 16 + g * 4;
                union { uint32_t w[2]; ushort4 v; } o;
                o.w[0] = cvt_pk(acc[mi][ni][0], acc[mi][ni][1]);
                o.w[1] = cvt_pk(acc[mi][ni][2], acc[mi][ni][3]);
                *(ushort4*)&C[(size_t)row * QKV_N + col] = o.v;
            }
    } else {
        const int h_ = ((n0 - 2 * DMODEL) >> 6) + wc;
#pragma unroll
        for (int mi = 0; mi < 8; ++mi)
#pragma unroll
            for (int ni = 0; ni < 4; ++ni) {
                const int row = m0 + wr * 128 + mi * 16 + r;
                const int b_ = row >> 11, s_ = row & (SEQ - 1);
                const int hd0 = ni * 16 + g * 4;
                union { uint32_t w[2]; u16 t[4]; } o;
                o.w[0] = cvt_pk(acc[mi][ni][0], acc[mi][ni][1]);
                o.w[1] = cvt_pk(acc[mi][ni][2], acc[mi][ni][3]);
                const size_t base =
                    ((size_t)(b_ * NH + h_) * HDIM + hd0) * SEQ + s_;
                Vt[base] = o.t[0];
                Vt[base + SEQ] = o.t[1];
                Vt[base + 2 * SEQ] = o.t[2];
                Vt[base + 3 * SEQ] = o.t[3];
            }
    }
}

// ---- kernel 3: proj GEMM, 64x128 tile (unchanged from round 6) -------
__global__ __launch_bounds__(256) void k_gemm_proj(const u16* __restrict__ A,
                                                   const u16* __restrict__ BT,
                                                   float* __restrict__ C) {
    __shared__ __align__(16) u16 As[64 * 64];
    __shared__ __align__(16) u16 Bs[128 * 64];
    const int tid = threadIdx.x;
    const int wid = tid >> 6, lane = tid & 63;
    const int r = lane & 15, g = lane >> 4;
    const int m0 = blockIdx.y * 64, n0 = blockIdx.x * 128;
    const int srow = lane >> 3, scol = (lane & 7) * 8;
    const int K = DMODEL;
    f32x4 acc[4][2] = {};
    for (int k0 = 0; k0 < K; k0 += 64) {
#pragma unroll
        for (int i = 0; i < 2; ++i) {
            const int li = wid * 2 + i;
            gl_lds16(A + (size_t)(m0 + li * 8 + srow) * K + k0 + scol, &As[li * 512]);
        }
#pragma unroll
        for (int i = 0; i < 4; ++i) {
            const int li = wid * 4 + i;
            gl_lds16(BT + (size_t)(n0 + li * 8 + srow) * K + k0 + scol, &Bs[li * 512]);
        }
        __syncthreads();
#pragma unroll
        for (int kk = 0; kk < 2; ++kk) {
            bf16x8 af[4], bfr[2];
#pragma unroll
            for (int mi = 0; mi < 4; ++mi)
                af[mi] = *(const bf16x8*)&As[(mi * 16 + r) * 64 + kk * 32 + g * 8];
#pragma unroll
            for (int ni = 0; ni < 2; ++ni)
                bfr[ni] = *(const bf16x8*)&Bs[(wid * 32 + ni * 16 + r) * 64 + kk * 32 + g * 8];
#pragma unroll
            for (int mi = 0; mi < 4; ++mi)
#pragma unroll
                for (int ni = 0; ni < 2; ++ni)
                    acc[mi][ni] = __builtin_amdgcn_mfma_f32_16x16x32_bf16(
                        bfr[ni], af[mi], acc[mi][ni], 0, 0, 0);
        }
        __syncthreads();
    }
#pragma unroll
    for (int mi = 0; mi < 4; ++mi)
#pragma unroll
        for (int ni = 0; ni < 2; ++ni) {
            const int row = m0 + mi * 16 + r;
            const int col = n0 + wid * 32 + ni * 16 + g * 4;
            float4 vv;
            vv.x = acc[mi][ni][0]; vv.y = acc[mi][ni][1];
            vv.z = acc[mi][ni][2]; vv.w = acc[mi][ni][3];
            *(float4*)&C[(size_t)row * DMODEL + col] = vv;
        }
}

// ---- kernel 4: flash attention v6 ------------------------------------
// Round-6 structure + (a) counted-vmcnt 2-deep pipeline: K(t+2) staged
// into Ks[cur] right after QK^T's barrier frees it, V(t+2) after PV's
// barrier; per-tile wait is vmcnt(4) (tile t+2's 4 loads stay in flight),
// never 0 in steady state. (b) lsum via ones-MFMA: Sigma-p accumulated on
// the idle MFMA pipe (output col=q), removing 16 VALU adds/tile and the
// epilogue cross-lane reduce.
__global__ __launch_bounds__(256) void k_attn(const u16* __restrict__ qkv,
                                              const u16* __restrict__ Vt,
                                              u16* __restrict__ O) {
    __shared__ __align__(16) u16 Ks[2][4096];
    __shared__ __align__(16) u16 Vs[2][4096];
    const int bh = blockIdx.y;
    const int b = bh >> 4, h = bh & 15;
    const int q0 = blockIdx.x * 64;
    const int tid = threadIdx.x, wid = tid >> 6, lane = tid & 63;
    const int r = lane & 15, g = lane >> 4;

    const size_t qbase = (size_t)(b * SEQ + q0 + wid * 16 + r) * QKV_N + h * HDIM;
    const bf16x8 qf0 = *(const bf16x8*)&qkv[qbase + g * 8];
    const bf16x8 qf1 = *(const bf16x8*)&qkv[qbase + 32 + g * 8];

    const short one_b = (short)0x3F80;               // bf16 1.0
    const bf16x8 ones = {one_b, one_b, one_b, one_b, one_b, one_b, one_b, one_b};

    float mL = -1e30f;
    f32x4 oacc[4] = {};
    f32x4 lacc = {};
    const int kc0 = wid * 2;

    const u16* kp[2];
    const u16* vp[2];
    int kdst[2], vdst[2];
#pragma unroll
    for (int i = 0; i < 2; ++i) {
        const int kc = kc0 + i;
        const int ksrow = (kc >> 2) * 32 + g * 8 + (kc & 1) * 4 + ((lane >> 2) & 3);
        const int kscol = ((kc >> 1) & 1) * 32 + (lane & 3) * 8;
        kp[i] = qkv + (size_t)(b * SEQ + ksrow) * QKV_N + DMODEL + h * HDIM + kscol;
        const int vhd = (kc & 3) * 16 + r;
        const int vsc = (kc >> 2) * 32 + g * 8;
        vp[i] = Vt + ((size_t)bh * HDIM + vhd) * SEQ + vsc;
        kdst[i] = kc * 512;
        vdst[i] = kc * 512;
    }

#define STAGE_K(BUF)                                                 \
    {                                                                \
        _Pragma("unroll") for (int i = 0; i < 2; ++i) {              \
            gl_lds16(kp[i], &Ks[BUF][kdst[i]]);                      \
            kp[i] += 64 * QKV_N;                                     \
        }                                                            \
    }
#define STAGE_V(BUF)                                                 \
    {                                                                \
        _Pragma("unroll") for (int i = 0; i < 2; ++i) {              \
            gl_lds16(vp[i], &Vs[BUF][vdst[i]]);                      \
            vp[i] += 64;                                             \
        }                                                            \
    }

    // prologue: stage tiles 0 and 1, full drain
    STAGE_K(0); STAGE_V(0);
    STAGE_K(1); STAGE_V(1);
    asm volatile("s_waitcnt vmcnt(0)");
    __syncthreads();

    for (int t = 0; t < SEQ / 64; ++t) {
        const int cur = t & 1;

        // QK^T (swapped): reads Ks[cur]
        f32x4 sacc[4] = {};
        __builtin_amdgcn_s_setprio(1);
#pragma unroll
        for (int nf = 0; nf < 4; ++nf) {
            const int kbase = (nf & 1) * 2048 + (nf >> 1) * 512 +
                              (r >> 2) * 128 + (r & 3) * 32 + g * 8;
            bf16x8 kf0 = *(const bf16x8*)&Ks[cur][kbase];
            bf16x8 kf1 = *(const bf16x8*)&Ks[cur][kbase + 1024];
            sacc[nf] = __builtin_amdgcn_mfma_f32_16x16x32_bf16(kf0, qf0, sacc[nf], 0, 0, 0);
            sacc[nf] = __builtin_amdgcn_mfma_f32_16x16x32_bf16(kf1, qf1, sacc[nf], 0, 0, 0);
        }
        __builtin_amdgcn_s_setprio(0);
        BAR();                       // all waves done reading Ks[cur]
        if (t < SEQ / 64 - 2) STAGE_K(cur);   // K(t+2) -> Ks[cur]

        // softmax (lane-local fast path)
        float mt = F3(sacc[0][0], sacc[0][1], sacc[0][2]);
        mt = F3(mt, sacc[0][3], sacc[1][0]);
        mt = F3(mt, sacc[1][1], sacc[1][2]);
        mt = F3(mt, sacc[1][3], sacc[2][0]);
        mt = F3(mt, sacc[2][1], sacc[2][2]);
        mt = F3(mt, sacc[2][3], sacc[3][0]);
        mt = F3(mt, sacc[3][1], sacc[3][2]);
        mt = fmaxf(mt, sacc[3][3]);
        const float pm = mt * C2;
        if (!__all(pm <= mL + 8.f)) {
            float rm = pm;
            rm = fmaxf(rm, __shfl_xor(rm, 16, 64));
            rm = fmaxf(rm, __shfl_xor(rm, 32, 64));
            const float mNew = fmaxf(mL, rm);
            const float al = exp2f(mL - mNew);
            mL = mNew;
#pragma unroll
            for (int ht = 0; ht < 4; ++ht)
#pragma unroll
                for (int e = 0; e < 4; ++e) oacc[ht][e] *= al;
#pragma unroll
            for (int e = 0; e < 4; ++e) lacc[e] *= al;
        }
        float p[4][4];
#pragma unroll
        for (int nf = 0; nf < 4; ++nf)
#pragma unroll
            for (int e = 0; e < 4; ++e)
                p[nf][e] = exp2f(sacc[nf][e] * C2 - mL);

        union { uint32_t w[4]; bf16x8 v; } upf0, upf1;
        upf0.w[0] = cvt_pk(p[0][0], p[0][1]);
        upf0.w[1] = cvt_pk(p[0][2], p[0][3]);
        upf0.w[2] = cvt_pk(p[2][0], p[2][1]);
        upf0.w[3] = cvt_pk(p[2][2], p[2][3]);
        upf1.w[0] = cvt_pk(p[1][0], p[1][1]);
        upf1.w[1] = cvt_pk(p[1][2], p[1][3]);
        upf1.w[2] = cvt_pk(p[3][0], p[3][1]);
        upf1.w[3] = cvt_pk(p[3][2], p[3][3]);

        // PV + lsum-MFMA: reads Vs[cur]
        __builtin_amdgcn_s_setprio(1);
#pragma unroll
        for (int ht = 0; ht < 4; ++ht) {
            bf16x8 vf0 = *(const bf16x8*)&Vs[cur][ht * 512 + g * 128 + r * 8];
            bf16x8 vf1 = *(const bf16x8*)&Vs[cur][(4 + ht) * 512 + g * 128 + r * 8];
            oacc[ht] = __builtin_amdgcn_mfma_f32_16x16x32_bf16(vf0, upf0.v, oacc[ht], 0, 0, 0);
            oacc[ht] = __builtin_amdgcn_mfma_f32_16x16x32_bf16(vf1, upf1.v, oacc[ht], 0, 0, 0);
        }
        lacc = __builtin_amdgcn_mfma_f32_16x16x32_bf16(ones, upf0.v, lacc, 0, 0, 0);
        lacc = __builtin_amdgcn_mfma_f32_16x16x32_bf16(ones, upf1.v, lacc, 0, 0, 0);
        __builtin_amdgcn_s_setprio(0);
        BAR();                       // all waves done reading Vs[cur]
        if (t < SEQ / 64 - 2) {
            STAGE_V(cur);            // V(t+2) -> Vs[cur]
            asm volatile("s_waitcnt vmcnt(4)");   // drain tile t+1, keep t+2 in flight
        } else if (t == SEQ / 64 - 2) {
            asm volatile("s_waitcnt vmcnt(0)");   // drain last staged tile
        }
        if (t < SEQ / 64 - 1) BAR(); // tile t+1 visible to all waves
    }
#undef STAGE_K
#undef STAGE_V

    const float inv = 1.0f / lacc[0];   // complete denominator, no reduce
    const size_t obase = (size_t)(b * SEQ + q0 + wid * 16 + r) * DMODEL + h * HDIM;
#pragma unroll
    for (int ht = 0; ht < 4; ++ht) {
        union { uint32_t w[2]; ushort4 v; } o;
        o.w[0] = cvt_pk(oacc[ht][0] * inv, oacc[ht][1] * inv);
        o.w[1] = cvt_pk(oacc[ht][2] * inv, oacc[ht][3] * inv);
        *(ushort4*)&O[obase + ht * 16 + g * 4] = o.v;
    }
}

// ---- launcher --------------------------------------------------------
extern "C" void kernel_launch(void* const* d_in, const int* in_sizes, int n_in,
                              void* d_out, int out_size, void* d_ws, size_t ws_size,
                              hipStream_t stream) {
    const float* x = (const float*)d_in[0];
    const float* Wqkv = (const float*)d_in[1];
    const float* Wproj = (const float*)d_in[2];
    float* out = (float*)d_out;

    u16* xb = (u16*)d_ws;                                  //  8 MB
    u16* WqkvT = xb + (size_t)MTOT * DMODEL;               //  6 MB
    u16* WprojT = WqkvT + (size_t)QKV_N * DMODEL;          //  2 MB
    u16* qkv = WprojT + (size_t)DMODEL * DMODEL;           // 24 MB (V third unused)
    u16* Vt = qkv + (size_t)MTOT * QKV_N;                  //  8 MB
    u16* Ob = Vt + (size_t)BATCH * NH * HDIM * SEQ;        //  8 MB

    hipFuncSetAttribute(reinterpret_cast<const void*>(k_gemm_qkv8),
                        hipFuncAttributeMaxDynamicSharedMemorySize, 131072);

    k_prep<<<dim3(3072), 256, 0, stream>>>(x, Wqkv, Wproj, xb, WqkvT, WprojT);
    k_gemm_qkv8<<<dim3(QKV_N / 256, MTOT / 256), 512, 131072, stream>>>(
        xb, WqkvT, qkv, Vt);
    k_attn<<<dim3(SEQ / 64, BATCH * NH), 256, 0, stream>>>(qkv, Vt, Ob);
    k_gemm_proj<<<dim3(DMODEL / 128, MTOT / 64), 256, 0, stream>>>(Ob, WprojT, out);
}